// Round 3
// baseline (262.555 us; speedup 1.0000x reference)
//
#include <hip/hip_runtime.h>
#include <hip/hip_bf16.h>

#define TOK 8192      // B*N
#define CDIM 384
#define HEADS 6
#define DH 64
#define HID 1536
#define SEQ 2048

// attention scale folded with log2(e): softmax computed in exp2 domain
#define QSCALE 0.18033688011112042f   // 0.125 * log2(e)

typedef short bf16x8 __attribute__((ext_vector_type(8)));
typedef short bf16x4 __attribute__((ext_vector_type(4)));
typedef float f32x4 __attribute__((ext_vector_type(4)));
typedef float f32x16 __attribute__((ext_vector_type(16)));
typedef void __attribute__((address_space(1))) GV;
typedef void __attribute__((address_space(3))) SV;

__device__ __forceinline__ short f2bf(float f) {
    __hip_bfloat16 h = __float2bfloat16(f);
    return *reinterpret_cast<short*>(&h);
}

__device__ __forceinline__ int pack_bf2(float a, float b) {
    __hip_bfloat162 h2 = __float22bfloat162_rn(make_float2(a, b));
    int r;
    __builtin_memcpy(&r, &h2, 4);
    return r;
}

__device__ __forceinline__ void gl_lds16(const short* g, short* lds) {
    // wave-collective: lane i's 16B -> lds_base + i*16 (lds must be wave-uniform)
    __builtin_amdgcn_global_load_lds((GV*)g, (SV*)lds, 16, 0, 0);
}

// tanh-approx gelu in exp2 domain: gelu(v) = v - v/(1 + exp2(A*v + B*v^3))
__device__ __forceinline__ float gelu_fast(float v) {
    const float A = 2.3022067f;       // 2*log2(e)*0.7978845608
    const float B = 0.1029442f;       // A*0.044715
    const float u = v * (A + B * v * v);
    return v - v / (1.0f + exp2f(u));
}

// ---------- fused LN(x)->bf16 + weight transpose/convert, one launch ----------
__global__ __launch_bounds__(128) void ln_trans(const float* __restrict__ x,
                                                const float* __restrict__ g,
                                                const float* __restrict__ bta,
                                                short* __restrict__ y,
                                                const float* __restrict__ w_qkv,
                                                const float* __restrict__ w_proj,
                                                const float* __restrict__ w_fc1,
                                                const float* __restrict__ w_fc2,
                                                short* __restrict__ qkvT,
                                                short* __restrict__ projT,
                                                short* __restrict__ fc1T,
                                                short* __restrict__ fc2T) {
    if (blockIdx.x < TOK) {
        const int row = blockIdx.x;
        const float* xr = x + (size_t)row * CDIM;
        const int t = threadIdx.x;
        float v0 = xr[t], v1 = xr[t + 128], v2 = xr[t + 256];
        float s = v0 + v1 + v2;
        float ss = v0 * v0 + v1 * v1 + v2 * v2;
#pragma unroll
        for (int off = 1; off < 64; off <<= 1) {
            s += __shfl_xor(s, off);
            ss += __shfl_xor(ss, off);
        }
        __shared__ float sh[4];
        const int wv = t >> 6;
        if ((t & 63) == 0) { sh[wv] = s; sh[2 + wv] = ss; }
        __syncthreads();
        s = sh[0] + sh[1];
        ss = sh[2] + sh[3];
        const float mu = s * (1.0f / CDIM);
        const float var = ss * (1.0f / CDIM) - mu * mu;
        const float rs = rsqrtf(var + 1e-6f);
        short* yr = y + (size_t)row * CDIM;
        yr[t]       = f2bf((v0 - mu) * rs * g[t]       + bta[t]);
        yr[t + 128] = f2bf((v1 - mu) * rs * g[t + 128] + bta[t + 128]);
        yr[t + 256] = f2bf((v2 - mu) * rs * g[t + 256] + bta[t + 256]);
        return;
    }
    int b = blockIdx.x - TOK;
    const float* w; short* o; int K, N, nb;
    if (b < 432)       { w = w_qkv;  o = qkvT;  K = 384;  N = 1152; nb = 36; }
    else if (b < 576)  { b -= 432;  w = w_proj; o = projT; K = 384;  N = 384;  nb = 12; }
    else if (b < 1152) { b -= 576;  w = w_fc1;  o = fc1T;  K = 384;  N = 1536; nb = 48; }
    else               { b -= 1152; w = w_fc2;  o = fc2T;  K = 1536; N = 384;  nb = 12; }
    const int bx = (b % nb) * 32, by = (b / nb) * 32;
    __shared__ float t[32][33];
    const int tx = threadIdx.x & 31, ty = threadIdx.x >> 5;
#pragma unroll
    for (int i = 0; i < 8; ++i)
        t[ty + i * 4][tx] = w[(size_t)(by + ty + i * 4) * N + bx + tx];
    __syncthreads();
#pragma unroll
    for (int i = 0; i < 8; ++i)
        o[(size_t)(bx + ty + i * 4) * K + by + tx] = f2bf(t[tx][ty + i * 4]);
}

// -------------------- LayerNorm (standalone, for LN2) --------------------
__global__ __launch_bounds__(128) void ln_kernel(const float* __restrict__ x,
                                                 const float* __restrict__ g,
                                                 const float* __restrict__ bta,
                                                 short* __restrict__ y) {
    const int row = blockIdx.x;
    const float* xr = x + (size_t)row * CDIM;
    const int t = threadIdx.x;
    float v0 = xr[t], v1 = xr[t + 128], v2 = xr[t + 256];
    float s = v0 + v1 + v2;
    float ss = v0 * v0 + v1 * v1 + v2 * v2;
#pragma unroll
    for (int off = 1; off < 64; off <<= 1) {
        s += __shfl_xor(s, off);
        ss += __shfl_xor(ss, off);
    }
    __shared__ float sh[4];
    const int wv = t >> 6;
    if ((t & 63) == 0) { sh[wv] = s; sh[2 + wv] = ss; }
    __syncthreads();
    s = sh[0] + sh[1];
    ss = sh[2] + sh[3];
    const float mu = s * (1.0f / CDIM);
    const float var = ss * (1.0f / CDIM) - mu * mu;
    const float rs = rsqrtf(var + 1e-6f);
    short* yr = y + (size_t)row * CDIM;
    yr[t]       = f2bf((v0 - mu) * rs * g[t]       + bta[t]);
    yr[t + 128] = f2bf((v1 - mu) * rs * g[t + 128] + bta[t + 128]);
    yr[t + 256] = f2bf((v2 - mu) * rs * g[t + 256] + bta[t + 256]);
}

// -------------------- bf16 MFMA GEMM: C = A[M,K] @ WT[N,K]^T + bias ----------------
// BK=64. MT=4: 128x128 (2x2 waves). MT=1: 64x64 (4x1 waves, balanced grids for N=384).
// MODE 0: fp32 out (+optional resid).  MODE 1: gelu -> bf16 out.  MODE 2: qkv scatter.
template <int MODE, int MT>
__global__ __launch_bounds__(256) void mfma_gemm(const short* __restrict__ A,
                                                 const short* __restrict__ WT,
                                                 const float* __restrict__ bias,
                                                 const float* __restrict__ resid,
                                                 float* __restrict__ outF,
                                                 short* __restrict__ outB,
                                                 short* __restrict__ qb,
                                                 short* __restrict__ kb,
                                                 short* __restrict__ vtb,
                                                 int M, int N, int K) {
    constexpr int BN = (MT == 4) ? 128 : 64;
    constexpr int BM = (MT == 1) ? 64 : 128;
    __shared__ __align__(16) short As[BM * 64];
    __shared__ __align__(16) short Bs[BN * 64];

    const int tid  = threadIdx.x;
    const int w    = tid >> 6;
    const int lane = tid & 63;
    const int quad = lane >> 4;
    const int n15  = lane & 15;
    const int wr   = (MT == 4) ? (w >> 1) : w;
    const int wc   = (MT == 4) ? (w & 1) : 0;
    const int m0   = blockIdx.y * BM;
    const int n0   = blockIdx.x * BN;
    const int swz  = n15 & 7;    // fragment-read swizzle (row&7 == n15&7)

    f32x4 acc[MT][4];
#pragma unroll
    for (int i = 0; i < MT; ++i)
#pragma unroll
        for (int j = 0; j < 4; ++j) {
            acc[i][j][0] = 0; acc[i][j][1] = 0; acc[i][j][2] = 0; acc[i][j][3] = 0;
        }

    for (int k0 = 0; k0 < K; k0 += 64) {
        __syncthreads();
        // tiles: rows x 8 chunks (16B); phys chunk p holds logical p^(r&7)
#pragma unroll
        for (int i = 0; i < BM / 32; ++i) {
            const int c = i * 256 + tid;
            const int r = c >> 3, p = c & 7;
            gl_lds16(A + (size_t)(m0 + r) * K + k0 + ((p ^ (r & 7)) * 8),
                     As + (i * 256 + w * 64) * 8);
        }
#pragma unroll
        for (int i = 0; i < BN / 32; ++i) {
            const int c = i * 256 + tid;
            const int r = c >> 3, p = c & 7;
            gl_lds16(WT + (size_t)(n0 + r) * K + k0 + ((p ^ (r & 7)) * 8),
                     Bs + (i * 256 + w * 64) * 8);
        }
        __syncthreads();

#pragma unroll
        for (int kk = 0; kk < 2; ++kk) {
            bf16x8 af[MT], bfr[4];
#pragma unroll
            for (int mt = 0; mt < MT; ++mt)
                af[mt] = *(const bf16x8*)&As[(wr * (MT * 16) + mt * 16 + n15) * 64 +
                                             (((kk * 4 + quad) ^ swz) * 8)];
#pragma unroll
            for (int nt = 0; nt < 4; ++nt)
                bfr[nt] = *(const bf16x8*)&Bs[(wc * 64 + nt * 16 + n15) * 64 +
                                              (((kk * 4 + quad) ^ swz) * 8)];
#pragma unroll
            for (int mt = 0; mt < MT; ++mt)
#pragma unroll
                for (int nt = 0; nt < 4; ++nt)
                    acc[mt][nt] = __builtin_amdgcn_mfma_f32_16x16x32_bf16(af[mt], bfr[nt], acc[mt][nt], 0, 0, 0);
        }
    }

    // epilogue: row = m0 + wr*(MT*16) + mt*16 + quad*4 + rr, col = n0 + wc*64 + nt*16 + n15
#pragma unroll
    for (int nt = 0; nt < 4; ++nt) {
        const int col = n0 + wc * 64 + nt * 16 + n15;
        const float bv = bias[col];
        if constexpr (MODE == 2) {
            const int part = col / CDIM;
            const int rem  = col - part * CDIM;
            const int h    = rem >> 6;
            const int d    = rem & 63;
#pragma unroll
            for (int mt = 0; mt < MT; ++mt) {
                const int r0 = m0 + wr * (MT * 16) + mt * 16 + quad * 4;   // rr=0 row
                const int bi = r0 >> 11;
                const int n  = r0 & 2047;                                   // 4-aligned
                if (part == 2) {
                    short4 pkv;
                    pkv.x = f2bf(acc[mt][nt][0] + bv);
                    pkv.y = f2bf(acc[mt][nt][1] + bv);
                    pkv.z = f2bf(acc[mt][nt][2] + bv);
                    pkv.w = f2bf(acc[mt][nt][3] + bv);
                    *(short4*)&vtb[((size_t)(bi * HEADS + h) * DH + d) * SEQ + n] = pkv;
                } else {
                    short* dst = (part == 0 ? qb : kb) +
                                 ((size_t)(bi * HEADS + h) * SEQ + n) * DH + d;
#pragma unroll
                    for (int rr = 0; rr < 4; ++rr) {
                        float o = acc[mt][nt][rr] + bv;
                        if (part == 0) o *= QSCALE;   // attention scale + log2e folding
                        dst[(size_t)rr * DH] = f2bf(o);
                    }
                }
            }
        } else {
#pragma unroll
            for (int mt = 0; mt < MT; ++mt)
#pragma unroll
                for (int rr = 0; rr < 4; ++rr) {
                    const int r = m0 + wr * (MT * 16) + mt * 16 + quad * 4 + rr;
                    float o = acc[mt][nt][rr] + bv;
                    if constexpr (MODE == 1) {
                        outB[(size_t)r * N + col] = f2bf(gelu_fast(o));
                    } else {
                        if (resid) o += resid[(size_t)r * N + col];
                        outF[(size_t)r * N + col] = o;
                    }
                }
        }
    }
}

// ---------- bf16 MFMA flash attention: 32x32 MFMA, dbuf LDS staging, counted vmcnt ----------
// r0 (67us): coalesced gl_lds staging, per-iter vmcnt(0) drain = serial L2 latency.
// r1 (101us): reg-direct frags, uncoalesced per-lane loads.
// r2 (73us): reg-prefetch pipeline spilled to scratch (WRITE_SIZE 6->15 MB), VGPR-bound.
// Now: zero-register pipeline. Tiles are wave-private (k-split, no in-loop barriers), so
// double-buffer the per-wave LDS and use a COUNTED wait: issue 8 gl_lds16 for tile t+1,
// s_waitcnt vmcnt(8) -> only tile t's loads must land; t+1's stay in flight under the
// full compute body. 2 waves/block (128 thr, 2-way k-split, 32 iters) keeps LDS at
// 32 KB -> 5 blocks/CU = 10 waves/CU. Compute path unchanged from r2 (verified).
__global__ __launch_bounds__(128, 2) void attn_mfma(const short* __restrict__ qb,
                                                    const short* __restrict__ kb,
                                                    const short* __restrict__ vtb,
                                                    short* __restrict__ outp) {
    // LDS 32768 B: loop: wave w at w*16384: buf0 {K 4K | V 4K} buf1 {K 4K | V 4K}
    //              merge: 2 x [32][65] fp32 O partials (16640 B) + 2x32 l
    __shared__ __align__(16) char smem[32768];

    // XCD-local decode: 8 slots x 3 heads x 64 q-tiles of 32 rows
    const int bid = blockIdx.x;
    const int x   = bid & 7;
    const int j   = bid >> 3;              // 0..191
    const int bh  = x * 3 + (j >> 6);      // 0..23
    const int qt  = j & 63;                // 32-row tile index
    const int bi  = bh / HEADS;
    const int h   = bh - bi * HEADS;

    const int tid  = threadIdx.x;
    const int w    = tid >> 6;             // 0..1
    const int lane = tid & 63;
    const int l31  = lane & 31;
    const int hi   = lane >> 5;

    const size_t headoff = (size_t)bh * SEQ * DH;

    // Q B-fragments (loop-invariant, one-time read): col n = q = l31, k = kc*16 + hi*8 + j
    bf16x8 qf[4];
    {
        const short* qg = qb + headoff + (size_t)(qt * 32 + l31) * DH + hi * 8;
#pragma unroll
        for (int kc = 0; kc < 4; ++kc)
            qf[kc] = *(const bf16x8*)(qg + kc * 16);
    }
    // drain Q loads so the in-loop vmcnt counting is exact
    asm volatile("s_waitcnt vmcnt(0)" ::: "memory");

    // staging bases (pre-swizzled sources, r0 addressing):
    // K tile: 32 ktok x 64 shorts, phys chunk p holds logical p^(row&7) -> 4 gl_lds16
    // V tile: 64 d x 32 shorts,    phys chunk p holds logical p^(row&3) -> 4 gl_lds16
    const int l3 = lane >> 3, l7 = lane & 7;
    const int l2 = lane >> 2, p4 = lane & 3;
    const short* kg = kb + headoff + (size_t)(w * 32 + l3) * DH + ((l7 ^ l3) * 8);
    const short* vg = vtb + (size_t)bh * DH * SEQ + (size_t)l2 * SEQ +
                      ((p4 ^ (l2 & 3)) * 8) + w * 32;

    // fragment-read lane constants
    const int swk = l31 & 7;               // K-tile row swizzle
    const int swv = l31 & 3;               // V-tile row swizzle
    const int krd = l31 * 64;
    const int vrd = l31 * 32;

    f32x16 O0 = {}, O1 = {};
    float lp = 0.0f;
    const f32x16 Zc = {};

    // stage(t): 8 wave-collective loads into buf (t&1); dest base wave-uniform
#define STAGE(tt)                                                                  \
    {                                                                              \
        short* Kd = (short*)(smem + w * 16384 + ((tt) & 1) * 8192);                \
        const short* kgt = kg + (size_t)(tt) * 64 * DH;                            \
        const short* vgt = vg + (tt) * 64;                                         \
        _Pragma("unroll")                                                          \
        for (int i = 0; i < 4; ++i) {                                              \
            gl_lds16(kgt + i * 512, Kd + i * 512);                                 \
            gl_lds16(vgt + (size_t)i * 16 * SEQ, Kd + 2048 + i * 512);             \
        }                                                                          \
    }

    STAGE(0);   // prologue: tile 0 in flight

#pragma unroll 2
    for (int t = 0; t < SEQ / 64; ++t) {        // 32 wave-private 32-ktok windows
        if (t < SEQ / 64 - 1) {
            STAGE(t + 1);                        // 8 more in flight (16 total)
            asm volatile("s_waitcnt vmcnt(8)" ::: "memory");   // tile t landed
        } else {
            asm volatile("s_waitcnt vmcnt(0)" ::: "memory");
        }
        __builtin_amdgcn_wave_barrier();        // pin LDS reads below the wait

        const short* Klb  = (const short*)(smem + w * 16384 + (t & 1) * 8192);
        const short* Vtlb = Klb + 2048;

        // K A-frags: m=ktok=l31, k=d=kc*16+hi*8+j -> logical chunk kc*2+hi
        bf16x8 kf0 = *(const bf16x8*)&Klb[krd + (((0 + hi) ^ swk) * 8)];
        bf16x8 kf1 = *(const bf16x8*)&Klb[krd + (((2 + hi) ^ swk) * 8)];
        bf16x8 kf2 = *(const bf16x8*)&Klb[krd + (((4 + hi) ^ swk) * 8)];
        bf16x8 kf3 = *(const bf16x8*)&Klb[krd + (((6 + hi) ^ swk) * 8)];

        // S^T[ktok][q] = K * Q^T over d=64: reg r -> ktok (r&3)+8*(r>>2)+4*hi, col q=l31
        f32x16 S = __builtin_amdgcn_mfma_f32_32x32x16_bf16(kf0, qf[0], Zc, 0, 0, 0);
        S = __builtin_amdgcn_mfma_f32_32x32x16_bf16(kf1, qf[1], S, 0, 0, 0);
        S = __builtin_amdgcn_mfma_f32_32x32x16_bf16(kf2, qf[2], S, 0, 0, 0);
        S = __builtin_amdgcn_mfma_f32_32x32x16_bf16(kf3, qf[3], S, 0, 0, 0);

        // V^T A-frags: m=d=l31(+32), k=ktok chunk (v00/v10: hi, v01/v11: 2+hi)
        bf16x8 v00 = *(const bf16x8*)&Vtlb[vrd + ((hi ^ swv) * 8)];
        bf16x8 v01 = *(const bf16x8*)&Vtlb[vrd + (((2 + hi) ^ swv) * 8)];
        bf16x8 v10 = *(const bf16x8*)&Vtlb[1024 + vrd + ((hi ^ swv) * 8)];
        bf16x8 v11 = *(const bf16x8*)&Vtlb[1024 + vrd + (((2 + hi) ^ swv) * 8)];

        // no-max exp2 softmax (scores pre-scaled by 0.125*log2e at qkv epilogue)
        float e[16];
#pragma unroll
        for (int r = 0; r < 16; ++r) e[r] = exp2f(S[r]);
        lp += (((e[0] + e[1]) + (e[2] + e[3])) + ((e[4] + e[5]) + (e[6] + e[7]))) +
              (((e[8] + e[9]) + (e[10] + e[11])) + ((e[12] + e[13]) + (e[14] + e[15])));

        // P^T B-frags: need k = hi*8+j per 16-ktok chunk; swap(w0,w2) -> frag words 0,2
        int p0 = pack_bf2(e[0], e[1]),  p1 = pack_bf2(e[2], e[3]);
        int p2 = pack_bf2(e[4], e[5]),  p3 = pack_bf2(e[6], e[7]);
        asm("v_permlane32_swap_b32 %0, %1" : "+v"(p0), "+v"(p2));
        asm("v_permlane32_swap_b32 %0, %1" : "+v"(p1), "+v"(p3));
        int p4w = pack_bf2(e[8], e[9]),  p5 = pack_bf2(e[10], e[11]);
        int p6 = pack_bf2(e[12], e[13]), p7 = pack_bf2(e[14], e[15]);
        asm("v_permlane32_swap_b32 %0, %1" : "+v"(p4w), "+v"(p6));
        asm("v_permlane32_swap_b32 %0, %1" : "+v"(p5), "+v"(p7));
        bf16x8 pf0, pf1;
        { int pw[4] = {p0, p1, p2, p3};   __builtin_memcpy(&pf0, pw, 16); }
        { int pw[4] = {p4w, p5, p6, p7};  __builtin_memcpy(&pf1, pw, 16); }

        // O^T[d][q] += V^T * P^T
        O0 = __builtin_amdgcn_mfma_f32_32x32x16_bf16(v00, pf0, O0, 0, 0, 0);
        O0 = __builtin_amdgcn_mfma_f32_32x32x16_bf16(v01, pf1, O0, 0, 0, 0);
        O1 = __builtin_amdgcn_mfma_f32_32x32x16_bf16(v10, pf0, O1, 0, 0, 0);
        O1 = __builtin_amdgcn_mfma_f32_32x32x16_bf16(v11, pf1, O1, 0, 0, 0);
    }
#undef STAGE

    // ---- merge: cross-wave sum of O^T and l via LDS (one-time) ----
    // lane halves hold complementary ktok subsets for l -> fold lane^32 first
    lp += __shfl_xor(lp, 32);

    __syncthreads();                       // all waves done with their K/V buffers
    float* Obuf = (float*)smem;            // wave p partial at p*2080 floats, [32][65]
    float* lbuf = (float*)(smem + 16640);  // [p][32]
    float* myO  = Obuf + w * 2080;
#pragma unroll
    for (int r = 0; r < 16; ++r) {
        const int d0 = (r & 3) + 8 * (r >> 2) + 4 * hi;
        myO[l31 * 65 + d0]      = O0[r];
        myO[l31 * 65 + 32 + d0] = O1[r];
    }
    if (hi == 0) lbuf[w * 32 + l31] = lp;
    __syncthreads();

    // 2048 outputs / 128 threads = 16 each: d = tid&63 (coalesced), q = (tid>>6)*16+i
    const int d  = tid & 63;
    const int qh = tid >> 6;
#pragma unroll
    for (int i = 0; i < 16; ++i) {
        const int q = qh * 16 + i;
        const float l = lbuf[q] + lbuf[32 + q];
        const float s = Obuf[q * 65 + d] + Obuf[2080 + q * 65 + d];
        outp[(size_t)(bi * SEQ + qt * 32 + q) * CDIM + h * DH + d] = f2bf(s / l);
    }
}

extern "C" void kernel_launch(void* const* d_in, const int* in_sizes, int n_in,
                              void* d_out, int out_size, void* d_ws, size_t ws_size,
                              hipStream_t stream) {
    const float* x      = (const float*)d_in[0];
    const float* w_qkv  = (const float*)d_in[1];
    const float* b_qkv  = (const float*)d_in[2];
    const float* w_proj = (const float*)d_in[3];
    const float* b_proj = (const float*)d_in[4];
    const float* w_fc1  = (const float*)d_in[5];
    const float* b_fc1  = (const float*)d_in[6];
    const float* w_fc2  = (const float*)d_in[7];
    const float* b_fc2  = (const float*)d_in[8];
    const float* g1     = (const float*)d_in[9];
    const float* beta1  = (const float*)d_in[10];
    const float* g2     = (const float*)d_in[11];
    const float* beta2  = (const float*)d_in[12];
    float* out = (float*)d_out;

    short* qkvT = (short*)d_ws;                         // [1152][384]
    short* projT = qkvT + 1152 * 384;                   // [384][384]
    short* fc1T  = projT + 384 * 384;                   // [1536][384]
    short* fc2T  = fc1T + 1536 * 384;                   // [384][1536]
    short* y     = fc2T + 384 * 1536;                   // [TOK][384]
    short* qb    = y + (size_t)TOK * 384;
    short* kb    = qb + (size_t)TOK * 384;
    short* vtb   = kb + (size_t)TOK * 384;
    short* attn  = vtb + (size_t)TOK * 384;             // [TOK][384]
    short* hbuf  = attn + (size_t)TOK * 384;            // [TOK][1536]

    // 1) LN1 + all weight transposes, one launch
    ln_trans<<<TOK + 1728, 128, 0, stream>>>(x, g1, beta1, y,
                                             w_qkv, w_proj, w_fc1, w_fc2,
                                             qkvT, projT, fc1T, fc2T);
    // 2) q/k/vt = y @ w_qkv + b_qkv   (MFMA, scatter epilogue)
    mfma_gemm<2, 4><<<dim3(1152 / 128, TOK / 128), 256, 0, stream>>>(
        y, qkvT, b_qkv, nullptr, nullptr, nullptr, qb, kb, vtb, TOK, 3 * CDIM, CDIM);
    // 3) attn = flash_attention(q, k, vt) -> bf16  (32x32 MFMA, dbuf counted-vmcnt)
    attn_mfma<<<1536, 128, 0, stream>>>(qb, kb, vtb, attn);
    // 4) out(x1) = x + attn @ w_proj + b_proj
    mfma_gemm<0, 1><<<dim3(CDIM / 64, TOK / 64), 256, 0, stream>>>(
        attn, projT, b_proj, x, out, nullptr, nullptr, nullptr, nullptr, TOK, CDIM, CDIM);
    // 5) y = bf16(LN(out, g2, beta2))
    ln_kernel<<<TOK, 128, 0, stream>>>(out, g2, beta2, y);
    // 6) h = bf16(gelu(y @ w_fc1 + b_fc1))
    mfma_gemm<1, 4><<<dim3(HID / 128, TOK / 128), 256, 0, stream>>>(
        y, fc1T, b_fc1, nullptr, nullptr, hbuf, nullptr, nullptr, nullptr, TOK, HID, CDIM);
    // 7) out = x1 + h @ w_fc2 + b_fc2  (in-place residual)
    mfma_gemm<0, 1><<<dim3(CDIM / 64, TOK / 64), 256, 0, stream>>>(
        hbuf, fc2T, b_fc2, out, out, nullptr, nullptr, nullptr, nullptr, TOK, CDIM, HID);
}

// Round 4
// 235.970 us; speedup vs baseline: 1.1127x; 1.1127x over previous
//
#include <hip/hip_runtime.h>
#include <hip/hip_bf16.h>

#define TOK 8192      // B*N
#define CDIM 384
#define HEADS 6
#define DH 64
#define HID 1536
#define SEQ 2048

// attention scale folded with log2(e): softmax computed in exp2 domain
#define QSCALE 0.18033688011112042f   // 0.125 * log2(e)

typedef short bf16x8 __attribute__((ext_vector_type(8)));
typedef short bf16x4 __attribute__((ext_vector_type(4)));
typedef float f32x4 __attribute__((ext_vector_type(4)));
typedef float f32x16 __attribute__((ext_vector_type(16)));
typedef void __attribute__((address_space(1))) GV;
typedef void __attribute__((address_space(3))) SV;

__device__ __forceinline__ short f2bf(float f) {
    __hip_bfloat16 h = __float2bfloat16(f);
    return *reinterpret_cast<short*>(&h);
}

__device__ __forceinline__ int pack_bf2(float a, float b) {
    __hip_bfloat162 h2 = __float22bfloat162_rn(make_float2(a, b));
    int r;
    __builtin_memcpy(&r, &h2, 4);
    return r;
}

__device__ __forceinline__ void gl_lds16(const short* g, short* lds) {
    // wave-collective: lane i's 16B -> lds_base + i*16 (lds must be wave-uniform)
    __builtin_amdgcn_global_load_lds((GV*)g, (SV*)lds, 16, 0, 0);
}

// tanh-approx gelu in exp2 domain: gelu(v) = v - v/(1 + exp2(A*v + B*v^3))
__device__ __forceinline__ float gelu_fast(float v) {
    const float A = 2.3022067f;       // 2*log2(e)*0.7978845608
    const float B = 0.1029442f;       // A*0.044715
    const float u = v * (A + B * v * v);
    return v - v / (1.0f + exp2f(u));
}

// ---------- fused LN(x)->bf16 + weight transpose/convert, one launch ----------
__global__ __launch_bounds__(128) void ln_trans(const float* __restrict__ x,
                                                const float* __restrict__ g,
                                                const float* __restrict__ bta,
                                                short* __restrict__ y,
                                                const float* __restrict__ w_qkv,
                                                const float* __restrict__ w_proj,
                                                const float* __restrict__ w_fc1,
                                                const float* __restrict__ w_fc2,
                                                short* __restrict__ qkvT,
                                                short* __restrict__ projT,
                                                short* __restrict__ fc1T,
                                                short* __restrict__ fc2T) {
    if (blockIdx.x < TOK) {
        const int row = blockIdx.x;
        const float* xr = x + (size_t)row * CDIM;
        const int t = threadIdx.x;
        float v0 = xr[t], v1 = xr[t + 128], v2 = xr[t + 256];
        float s = v0 + v1 + v2;
        float ss = v0 * v0 + v1 * v1 + v2 * v2;
#pragma unroll
        for (int off = 1; off < 64; off <<= 1) {
            s += __shfl_xor(s, off);
            ss += __shfl_xor(ss, off);
        }
        __shared__ float sh[4];
        const int wv = t >> 6;
        if ((t & 63) == 0) { sh[wv] = s; sh[2 + wv] = ss; }
        __syncthreads();
        s = sh[0] + sh[1];
        ss = sh[2] + sh[3];
        const float mu = s * (1.0f / CDIM);
        const float var = ss * (1.0f / CDIM) - mu * mu;
        const float rs = rsqrtf(var + 1e-6f);
        short* yr = y + (size_t)row * CDIM;
        yr[t]       = f2bf((v0 - mu) * rs * g[t]       + bta[t]);
        yr[t + 128] = f2bf((v1 - mu) * rs * g[t + 128] + bta[t + 128]);
        yr[t + 256] = f2bf((v2 - mu) * rs * g[t + 256] + bta[t + 256]);
        return;
    }
    int b = blockIdx.x - TOK;
    const float* w; short* o; int K, N, nb;
    if (b < 432)       { w = w_qkv;  o = qkvT;  K = 384;  N = 1152; nb = 36; }
    else if (b < 576)  { b -= 432;  w = w_proj; o = projT; K = 384;  N = 384;  nb = 12; }
    else if (b < 1152) { b -= 576;  w = w_fc1;  o = fc1T;  K = 384;  N = 1536; nb = 48; }
    else               { b -= 1152; w = w_fc2;  o = fc2T;  K = 1536; N = 384;  nb = 12; }
    const int bx = (b % nb) * 32, by = (b / nb) * 32;
    __shared__ float t[32][33];
    const int tx = threadIdx.x & 31, ty = threadIdx.x >> 5;
#pragma unroll
    for (int i = 0; i < 8; ++i)
        t[ty + i * 4][tx] = w[(size_t)(by + ty + i * 4) * N + bx + tx];
    __syncthreads();
#pragma unroll
    for (int i = 0; i < 8; ++i)
        o[(size_t)(bx + ty + i * 4) * K + by + tx] = f2bf(t[tx][ty + i * 4]);
}

// -------------------- LayerNorm (standalone, for LN2) --------------------
__global__ __launch_bounds__(128) void ln_kernel(const float* __restrict__ x,
                                                 const float* __restrict__ g,
                                                 const float* __restrict__ bta,
                                                 short* __restrict__ y) {
    const int row = blockIdx.x;
    const float* xr = x + (size_t)row * CDIM;
    const int t = threadIdx.x;
    float v0 = xr[t], v1 = xr[t + 128], v2 = xr[t + 256];
    float s = v0 + v1 + v2;
    float ss = v0 * v0 + v1 * v1 + v2 * v2;
#pragma unroll
    for (int off = 1; off < 64; off <<= 1) {
        s += __shfl_xor(s, off);
        ss += __shfl_xor(ss, off);
    }
    __shared__ float sh[4];
    const int wv = t >> 6;
    if ((t & 63) == 0) { sh[wv] = s; sh[2 + wv] = ss; }
    __syncthreads();
    s = sh[0] + sh[1];
    ss = sh[2] + sh[3];
    const float mu = s * (1.0f / CDIM);
    const float var = ss * (1.0f / CDIM) - mu * mu;
    const float rs = rsqrtf(var + 1e-6f);
    short* yr = y + (size_t)row * CDIM;
    yr[t]       = f2bf((v0 - mu) * rs * g[t]       + bta[t]);
    yr[t + 128] = f2bf((v1 - mu) * rs * g[t + 128] + bta[t + 128]);
    yr[t + 256] = f2bf((v2 - mu) * rs * g[t + 256] + bta[t + 256]);
}

// -------------------- bf16 MFMA GEMM: C = A[M,K] @ WT[N,K]^T + bias ----------------
// BK=64. MT=4: 128x128 (2x2 waves). MT=1: 64x64 (4x1 waves, balanced grids for N=384).
// MODE 0: fp32 out (+optional resid).  MODE 1: gelu -> bf16 out.  MODE 2: qkv scatter.
template <int MODE, int MT>
__global__ __launch_bounds__(256) void mfma_gemm(const short* __restrict__ A,
                                                 const short* __restrict__ WT,
                                                 const float* __restrict__ bias,
                                                 const float* __restrict__ resid,
                                                 float* __restrict__ outF,
                                                 short* __restrict__ outB,
                                                 short* __restrict__ qb,
                                                 short* __restrict__ kb,
                                                 short* __restrict__ vtb,
                                                 int M, int N, int K) {
    constexpr int BN = (MT == 4) ? 128 : 64;
    constexpr int BM = (MT == 1) ? 64 : 128;
    __shared__ __align__(16) short As[BM * 64];
    __shared__ __align__(16) short Bs[BN * 64];

    const int tid  = threadIdx.x;
    const int w    = tid >> 6;
    const int lane = tid & 63;
    const int quad = lane >> 4;
    const int n15  = lane & 15;
    const int wr   = (MT == 4) ? (w >> 1) : w;
    const int wc   = (MT == 4) ? (w & 1) : 0;
    const int m0   = blockIdx.y * BM;
    const int n0   = blockIdx.x * BN;
    const int swz  = n15 & 7;    // fragment-read swizzle (row&7 == n15&7)

    f32x4 acc[MT][4];
#pragma unroll
    for (int i = 0; i < MT; ++i)
#pragma unroll
        for (int j = 0; j < 4; ++j) {
            acc[i][j][0] = 0; acc[i][j][1] = 0; acc[i][j][2] = 0; acc[i][j][3] = 0;
        }

    for (int k0 = 0; k0 < K; k0 += 64) {
        __syncthreads();
        // tiles: rows x 8 chunks (16B); phys chunk p holds logical p^(r&7)
#pragma unroll
        for (int i = 0; i < BM / 32; ++i) {
            const int c = i * 256 + tid;
            const int r = c >> 3, p = c & 7;
            gl_lds16(A + (size_t)(m0 + r) * K + k0 + ((p ^ (r & 7)) * 8),
                     As + (i * 256 + w * 64) * 8);
        }
#pragma unroll
        for (int i = 0; i < BN / 32; ++i) {
            const int c = i * 256 + tid;
            const int r = c >> 3, p = c & 7;
            gl_lds16(WT + (size_t)(n0 + r) * K + k0 + ((p ^ (r & 7)) * 8),
                     Bs + (i * 256 + w * 64) * 8);
        }
        __syncthreads();

#pragma unroll
        for (int kk = 0; kk < 2; ++kk) {
            bf16x8 af[MT], bfr[4];
#pragma unroll
            for (int mt = 0; mt < MT; ++mt)
                af[mt] = *(const bf16x8*)&As[(wr * (MT * 16) + mt * 16 + n15) * 64 +
                                             (((kk * 4 + quad) ^ swz) * 8)];
#pragma unroll
            for (int nt = 0; nt < 4; ++nt)
                bfr[nt] = *(const bf16x8*)&Bs[(wc * 64 + nt * 16 + n15) * 64 +
                                              (((kk * 4 + quad) ^ swz) * 8)];
#pragma unroll
            for (int mt = 0; mt < MT; ++mt)
#pragma unroll
                for (int nt = 0; nt < 4; ++nt)
                    acc[mt][nt] = __builtin_amdgcn_mfma_f32_16x16x32_bf16(af[mt], bfr[nt], acc[mt][nt], 0, 0, 0);
        }
    }

    // epilogue: row = m0 + wr*(MT*16) + mt*16 + quad*4 + rr, col = n0 + wc*64 + nt*16 + n15
#pragma unroll
    for (int nt = 0; nt < 4; ++nt) {
        const int col = n0 + wc * 64 + nt * 16 + n15;
        const float bv = bias[col];
        if constexpr (MODE == 2) {
            const int part = col / CDIM;
            const int rem  = col - part * CDIM;
            const int h    = rem >> 6;
            const int d    = rem & 63;
#pragma unroll
            for (int mt = 0; mt < MT; ++mt) {
                const int r0 = m0 + wr * (MT * 16) + mt * 16 + quad * 4;   // rr=0 row
                const int bi = r0 >> 11;
                const int n  = r0 & 2047;                                   // 4-aligned
                if (part == 2) {
                    short4 pkv;
                    pkv.x = f2bf(acc[mt][nt][0] + bv);
                    pkv.y = f2bf(acc[mt][nt][1] + bv);
                    pkv.z = f2bf(acc[mt][nt][2] + bv);
                    pkv.w = f2bf(acc[mt][nt][3] + bv);
                    *(short4*)&vtb[((size_t)(bi * HEADS + h) * DH + d) * SEQ + n] = pkv;
                } else {
                    short* dst = (part == 0 ? qb : kb) +
                                 ((size_t)(bi * HEADS + h) * SEQ + n) * DH + d;
#pragma unroll
                    for (int rr = 0; rr < 4; ++rr) {
                        float o = acc[mt][nt][rr] + bv;
                        if (part == 0) o *= QSCALE;   // attention scale + log2e folding
                        dst[(size_t)rr * DH] = f2bf(o);
                    }
                }
            }
        } else {
#pragma unroll
            for (int mt = 0; mt < MT; ++mt)
#pragma unroll
                for (int rr = 0; rr < 4; ++rr) {
                    const int r = m0 + wr * (MT * 16) + mt * 16 + quad * 4 + rr;
                    float o = acc[mt][nt][rr] + bv;
                    if constexpr (MODE == 1) {
                        outB[(size_t)r * N + col] = f2bf(gelu_fast(o));
                    } else {
                        if (resid) o += resid[(size_t)r * N + col];
                        outF[(size_t)r * N + col] = o;
                    }
                }
        }
    }
}

// ---------- bf16 MFMA flash attention: r0 structure + 32x32 compute ----------
// Evidence r0-r3: r0 (67us) is ~90% issue-saturated (VALU 63 + MFMA 27) -> cut
// instructions, keep structure. r1: reg-direct frags uncoalesced (dead). r2: 32x32
// compute works but reg-prefetch spilled. r3: 2-wave blocks halved TLP (92us).
// This version: r0's EXACT staging/occupancy (256 thr, 4-way k-split, 16 iters,
// gl_lds16 + per-iter vmcnt(0) drain, 33.8KB LDS -> 4 blocks/CU = 16 waves/CU)
// with the verified 32x32 compute body: 4 QK-MFMA + 4 PV-MFMA + in-register
// softmax (exp2, cvt_pk_bf16, permlane32_swap) + VALU l-tree. Per-iter issue
// drops ~330 -> ~200 cyc at identical memory behavior.
__global__ __launch_bounds__(256, 4) void attn_mfma(const short* __restrict__ qb,
                                                    const short* __restrict__ kb,
                                                    const short* __restrict__ vtb,
                                                    short* __restrict__ outp) {
    // LDS 33792 B: loop:  wave w: K tile 4KB + V tile 4KB at w*8192
    //              merge: 4 x [32][65] fp32 O partials (33280 B) + 4x32 l
    __shared__ __align__(16) char smem[33792];

    // XCD-local decode: 8 slots x 3 heads x 64 q-tiles of 32 rows
    const int bid = blockIdx.x;
    const int x   = bid & 7;
    const int j   = bid >> 3;              // 0..191
    const int bh  = x * 3 + (j >> 6);      // 0..23
    const int qt  = j & 63;                // 32-row tile index
    const int bi  = bh / HEADS;
    const int h   = bh - bi * HEADS;

    const int tid  = threadIdx.x;
    const int w    = tid >> 6;             // 0..3
    const int lane = tid & 63;
    const int l31  = lane & 31;
    const int hi   = lane >> 5;

    short* Kl  = (short*)(smem + w * 8192);
    short* Vtl = (short*)(smem + w * 8192 + 4096);

    const size_t headoff = (size_t)bh * SEQ * DH;

    // Q B-fragments (loop-invariant, one-time read): col n = q = l31, k = kc*16 + hi*8 + j
    bf16x8 qf[4];
    {
        const short* qg = qb + headoff + (size_t)(qt * 32 + l31) * DH + hi * 8;
#pragma unroll
        for (int kc = 0; kc < 4; ++kc)
            qf[kc] = *(const bf16x8*)(qg + kc * 16);
    }

    // staging bases (pre-swizzled sources, r0 addressing):
    // K tile: 32 ktok x 64 shorts, phys chunk p holds logical p^(row&7) -> 4 gl_lds16
    // V tile: 64 d x 32 shorts,    phys chunk p holds logical p^(row&3) -> 4 gl_lds16
    const int l3 = lane >> 3, l7 = lane & 7;
    const int l2 = lane >> 2, p4 = lane & 3;
    const short* kg = kb + headoff + (size_t)(w * 32 + l3) * DH + ((l7 ^ l3) * 8);
    const short* vg = vtb + (size_t)bh * DH * SEQ + (size_t)l2 * SEQ +
                      ((p4 ^ (l2 & 3)) * 8) + w * 32;

    // fragment-read lane constants
    const int swk = l31 & 7;               // K-tile row swizzle
    const int swv = l31 & 3;               // V-tile row swizzle
    const int krd = l31 * 64;
    const int vrd = l31 * 32;

    f32x16 O0 = {}, O1 = {};
    float lp = 0.0f;
    const f32x16 Zc = {};

    for (int t = 0; t < SEQ / 128; ++t) {       // 16 iters; wave-private 32-ktok window
        // stage private tiles: K 4 instr (8 rows each), V 4 instr (16 rows each)
#pragma unroll
        for (int i = 0; i < 4; ++i) {
            gl_lds16(kg + i * 512, Kl + i * 512);
            gl_lds16(vg + (size_t)i * 16 * SEQ, Vtl + i * 512);
        }
        kg += 128 * DH;
        vg += 128;
        asm volatile("s_waitcnt vmcnt(0)" ::: "memory");
        __builtin_amdgcn_wave_barrier();        // pin LDS reads below the wait

        // K A-frags: m=ktok=l31, k=d=kc*16+hi*8+j -> logical chunk kc*2+hi
        bf16x8 kf0 = *(const bf16x8*)&Kl[krd + (((0 + hi) ^ swk) * 8)];
        bf16x8 kf1 = *(const bf16x8*)&Kl[krd + (((2 + hi) ^ swk) * 8)];
        bf16x8 kf2 = *(const bf16x8*)&Kl[krd + (((4 + hi) ^ swk) * 8)];
        bf16x8 kf3 = *(const bf16x8*)&Kl[krd + (((6 + hi) ^ swk) * 8)];

        // S^T[ktok][q] = K * Q^T over d=64: reg r -> ktok (r&3)+8*(r>>2)+4*hi, col q=l31
        f32x16 S = __builtin_amdgcn_mfma_f32_32x32x16_bf16(kf0, qf[0], Zc, 0, 0, 0);
        S = __builtin_amdgcn_mfma_f32_32x32x16_bf16(kf1, qf[1], S, 0, 0, 0);
        S = __builtin_amdgcn_mfma_f32_32x32x16_bf16(kf2, qf[2], S, 0, 0, 0);
        S = __builtin_amdgcn_mfma_f32_32x32x16_bf16(kf3, qf[3], S, 0, 0, 0);

        // V^T A-frags: m=d=l31(+32), k=ktok chunk (v00/v10: hi, v01/v11: 2+hi)
        bf16x8 v00 = *(const bf16x8*)&Vtl[vrd + ((hi ^ swv) * 8)];
        bf16x8 v01 = *(const bf16x8*)&Vtl[vrd + (((2 + hi) ^ swv) * 8)];
        bf16x8 v10 = *(const bf16x8*)&Vtl[1024 + vrd + ((hi ^ swv) * 8)];
        bf16x8 v11 = *(const bf16x8*)&Vtl[1024 + vrd + (((2 + hi) ^ swv) * 8)];

        // no-max exp2 softmax (scores pre-scaled by 0.125*log2e at qkv epilogue)
        float e[16];
#pragma unroll
        for (int r = 0; r < 16; ++r) e[r] = exp2f(S[r]);
        lp += (((e[0] + e[1]) + (e[2] + e[3])) + ((e[4] + e[5]) + (e[6] + e[7]))) +
              (((e[8] + e[9]) + (e[10] + e[11])) + ((e[12] + e[13]) + (e[14] + e[15])));

        // P^T B-frags: need k = hi*8+j per 16-ktok chunk; swap(w0,w2) -> frag words 0,2
        int p0 = pack_bf2(e[0], e[1]),  p1 = pack_bf2(e[2], e[3]);
        int p2 = pack_bf2(e[4], e[5]),  p3 = pack_bf2(e[6], e[7]);
        asm("v_permlane32_swap_b32 %0, %1" : "+v"(p0), "+v"(p2));
        asm("v_permlane32_swap_b32 %0, %1" : "+v"(p1), "+v"(p3));
        int p4w = pack_bf2(e[8], e[9]),  p5 = pack_bf2(e[10], e[11]);
        int p6 = pack_bf2(e[12], e[13]), p7 = pack_bf2(e[14], e[15]);
        asm("v_permlane32_swap_b32 %0, %1" : "+v"(p4w), "+v"(p6));
        asm("v_permlane32_swap_b32 %0, %1" : "+v"(p5), "+v"(p7));
        bf16x8 pf0, pf1;
        { int pw[4] = {p0, p1, p2, p3};   __builtin_memcpy(&pf0, pw, 16); }
        { int pw[4] = {p4w, p5, p6, p7};  __builtin_memcpy(&pf1, pw, 16); }

        // O^T[d][q] += V^T * P^T
        O0 = __builtin_amdgcn_mfma_f32_32x32x16_bf16(v00, pf0, O0, 0, 0, 0);
        O0 = __builtin_amdgcn_mfma_f32_32x32x16_bf16(v01, pf1, O0, 0, 0, 0);
        O1 = __builtin_amdgcn_mfma_f32_32x32x16_bf16(v10, pf0, O1, 0, 0, 0);
        O1 = __builtin_amdgcn_mfma_f32_32x32x16_bf16(v11, pf1, O1, 0, 0, 0);
    }

    // ---- merge: cross-wave sum of O^T and l via LDS (one-time) ----
    // lane halves hold complementary ktok subsets for l -> fold lane^32 first
    lp += __shfl_xor(lp, 32);

    __syncthreads();                       // all waves done with their K/V tiles
    float* Obuf = (float*)smem;            // wave p partial at p*2080 floats, [32][65]
    float* lbuf = (float*)(smem + 33280);  // [p][32]
    float* myO  = Obuf + w * 2080;
#pragma unroll
    for (int r = 0; r < 16; ++r) {
        const int d0 = (r & 3) + 8 * (r >> 2) + 4 * hi;
        myO[l31 * 65 + d0]      = O0[r];
        myO[l31 * 65 + 32 + d0] = O1[r];
    }
    if (hi == 0) lbuf[w * 32 + l31] = lp;
    __syncthreads();

    // wave w sums d-slice [w*16, w*16+16): lane (quad,n15) -> d = w*16+n15, q = quad*8+i
    const int quad = lane >> 4;
    const int n15  = lane & 15;
    const int d = w * 16 + n15;
#pragma unroll
    for (int i = 0; i < 8; ++i) {
        const int q = quad * 8 + i;
        const float l = lbuf[q] + lbuf[32 + q] + lbuf[64 + q] + lbuf[96 + q];
        const float s = Obuf[q * 65 + d] + Obuf[2080 + q * 65 + d] +
                        Obuf[4160 + q * 65 + d] + Obuf[6240 + q * 65 + d];
        outp[(size_t)(bi * SEQ + qt * 32 + q) * CDIM + h * DH + d] = f2bf(s / l);
    }
}

extern "C" void kernel_launch(void* const* d_in, const int* in_sizes, int n_in,
                              void* d_out, int out_size, void* d_ws, size_t ws_size,
                              hipStream_t stream) {
    const float* x      = (const float*)d_in[0];
    const float* w_qkv  = (const float*)d_in[1];
    const float* b_qkv  = (const float*)d_in[2];
    const float* w_proj = (const float*)d_in[3];
    const float* b_proj = (const float*)d_in[4];
    const float* w_fc1  = (const float*)d_in[5];
    const float* b_fc1  = (const float*)d_in[6];
    const float* w_fc2  = (const float*)d_in[7];
    const float* b_fc2  = (const float*)d_in[8];
    const float* g1     = (const float*)d_in[9];
    const float* beta1  = (const float*)d_in[10];
    const float* g2     = (const float*)d_in[11];
    const float* beta2  = (const float*)d_in[12];
    float* out = (float*)d_out;

    short* qkvT = (short*)d_ws;                         // [1152][384]
    short* projT = qkvT + 1152 * 384;                   // [384][384]
    short* fc1T  = projT + 384 * 384;                   // [1536][384]
    short* fc2T  = fc1T + 1536 * 384;                   // [384][1536]
    short* y     = fc2T + 384 * 1536;                   // [TOK][384]
    short* qb    = y + (size_t)TOK * 384;
    short* kb    = qb + (size_t)TOK * 384;
    short* vtb   = kb + (size_t)TOK * 384;
    short* attn  = vtb + (size_t)TOK * 384;             // [TOK][384]
    short* hbuf  = attn + (size_t)TOK * 384;            // [TOK][1536]

    // 1) LN1 + all weight transposes, one launch
    ln_trans<<<TOK + 1728, 128, 0, stream>>>(x, g1, beta1, y,
                                             w_qkv, w_proj, w_fc1, w_fc2,
                                             qkvT, projT, fc1T, fc2T);
    // 2) q/k/vt = y @ w_qkv + b_qkv   (MFMA, scatter epilogue)
    mfma_gemm<2, 4><<<dim3(1152 / 128, TOK / 128), 256, 0, stream>>>(
        y, qkvT, b_qkv, nullptr, nullptr, nullptr, qb, kb, vtb, TOK, 3 * CDIM, CDIM);
    // 3) attn = flash_attention(q, k, vt) -> bf16  (r0 staging, 32x32 compute)
    attn_mfma<<<1536, 256, 0, stream>>>(qb, kb, vtb, attn);
    // 4) out(x1) = x + attn @ w_proj + b_proj
    mfma_gemm<0, 1><<<dim3(CDIM / 64, TOK / 64), 256, 0, stream>>>(
        attn, projT, b_proj, x, out, nullptr, nullptr, nullptr, nullptr, TOK, CDIM, CDIM);
    // 5) y = bf16(LN(out, g2, beta2))
    ln_kernel<<<TOK, 128, 0, stream>>>(out, g2, beta2, y);
    // 6) h = bf16(gelu(y @ w_fc1 + b_fc1))
    mfma_gemm<1, 4><<<dim3(HID / 128, TOK / 128), 256, 0, stream>>>(
        y, fc1T, b_fc1, nullptr, nullptr, hbuf, nullptr, nullptr, nullptr, TOK, HID, CDIM);
    // 7) out = x1 + h @ w_fc2 + b_fc2  (in-place residual)
    mfma_gemm<0, 1><<<dim3(CDIM / 64, TOK / 64), 256, 0, stream>>>(
        hbuf, fc2T, b_fc2, out, out, nullptr, nullptr, nullptr, nullptr, TOK, CDIM, HID);
}

// Round 5
// 235.045 us; speedup vs baseline: 1.1170x; 1.0039x over previous
//
#include <hip/hip_runtime.h>
#include <hip/hip_bf16.h>

#define TOK 8192      // B*N
#define CDIM 384
#define HEADS 6
#define DH 64
#define HID 1536
#define SEQ 2048

// attention scale folded with log2(e): softmax computed in exp2 domain
#define QSCALE 0.18033688011112042f   // 0.125 * log2(e)

typedef short bf16x8 __attribute__((ext_vector_type(8)));
typedef short bf16x4 __attribute__((ext_vector_type(4)));
typedef float f32x4 __attribute__((ext_vector_type(4)));
typedef float f32x16 __attribute__((ext_vector_type(16)));
typedef void __attribute__((address_space(1))) GV;
typedef void __attribute__((address_space(3))) SV;

__device__ __forceinline__ short f2bf(float f) {
    __hip_bfloat16 h = __float2bfloat16(f);
    return *reinterpret_cast<short*>(&h);
}

__device__ __forceinline__ int pack_bf2(float a, float b) {
    __hip_bfloat162 h2 = __float22bfloat162_rn(make_float2(a, b));
    int r;
    __builtin_memcpy(&r, &h2, 4);
    return r;
}

__device__ __forceinline__ void gl_lds16(const short* g, short* lds) {
    // wave-collective: lane i's 16B -> lds_base + i*16 (lds must be wave-uniform)
    __builtin_amdgcn_global_load_lds((GV*)g, (SV*)lds, 16, 0, 0);
}

// tanh-approx gelu in exp2 domain: gelu(v) = v - v/(1 + exp2(A*v + B*v^3))
__device__ __forceinline__ float gelu_fast(float v) {
    const float A = 2.3022067f;       // 2*log2(e)*0.7978845608
    const float B = 0.1029442f;       // A*0.044715
    const float u = v * (A + B * v * v);
    return v - v / (1.0f + exp2f(u));
}

// ---------- fused LN(x)->bf16 + weight transpose/convert, one launch ----------
__global__ __launch_bounds__(128) void ln_trans(const float* __restrict__ x,
                                                const float* __restrict__ g,
                                                const float* __restrict__ bta,
                                                short* __restrict__ y,
                                                const float* __restrict__ w_qkv,
                                                const float* __restrict__ w_proj,
                                                const float* __restrict__ w_fc1,
                                                const float* __restrict__ w_fc2,
                                                short* __restrict__ qkvT,
                                                short* __restrict__ projT,
                                                short* __restrict__ fc1T,
                                                short* __restrict__ fc2T) {
    if (blockIdx.x < TOK) {
        const int row = blockIdx.x;
        const float* xr = x + (size_t)row * CDIM;
        const int t = threadIdx.x;
        float v0 = xr[t], v1 = xr[t + 128], v2 = xr[t + 256];
        float s = v0 + v1 + v2;
        float ss = v0 * v0 + v1 * v1 + v2 * v2;
#pragma unroll
        for (int off = 1; off < 64; off <<= 1) {
            s += __shfl_xor(s, off);
            ss += __shfl_xor(ss, off);
        }
        __shared__ float sh[4];
        const int wv = t >> 6;
        if ((t & 63) == 0) { sh[wv] = s; sh[2 + wv] = ss; }
        __syncthreads();
        s = sh[0] + sh[1];
        ss = sh[2] + sh[3];
        const float mu = s * (1.0f / CDIM);
        const float var = ss * (1.0f / CDIM) - mu * mu;
        const float rs = rsqrtf(var + 1e-6f);
        short* yr = y + (size_t)row * CDIM;
        yr[t]       = f2bf((v0 - mu) * rs * g[t]       + bta[t]);
        yr[t + 128] = f2bf((v1 - mu) * rs * g[t + 128] + bta[t + 128]);
        yr[t + 256] = f2bf((v2 - mu) * rs * g[t + 256] + bta[t + 256]);
        return;
    }
    int b = blockIdx.x - TOK;
    const float* w; short* o; int K, N, nb;
    if (b < 432)       { w = w_qkv;  o = qkvT;  K = 384;  N = 1152; nb = 36; }
    else if (b < 576)  { b -= 432;  w = w_proj; o = projT; K = 384;  N = 384;  nb = 12; }
    else if (b < 1152) { b -= 576;  w = w_fc1;  o = fc1T;  K = 384;  N = 1536; nb = 48; }
    else               { b -= 1152; w = w_fc2;  o = fc2T;  K = 1536; N = 384;  nb = 12; }
    const int bx = (b % nb) * 32, by = (b / nb) * 32;
    __shared__ float t[32][33];
    const int tx = threadIdx.x & 31, ty = threadIdx.x >> 5;
#pragma unroll
    for (int i = 0; i < 8; ++i)
        t[ty + i * 4][tx] = w[(size_t)(by + ty + i * 4) * N + bx + tx];
    __syncthreads();
#pragma unroll
    for (int i = 0; i < 8; ++i)
        o[(size_t)(bx + ty + i * 4) * K + by + tx] = f2bf(t[tx][ty + i * 4]);
}

// -------------------- LayerNorm (standalone, for LN2) --------------------
__global__ __launch_bounds__(128) void ln_kernel(const float* __restrict__ x,
                                                 const float* __restrict__ g,
                                                 const float* __restrict__ bta,
                                                 short* __restrict__ y) {
    const int row = blockIdx.x;
    const float* xr = x + (size_t)row * CDIM;
    const int t = threadIdx.x;
    float v0 = xr[t], v1 = xr[t + 128], v2 = xr[t + 256];
    float s = v0 + v1 + v2;
    float ss = v0 * v0 + v1 * v1 + v2 * v2;
#pragma unroll
    for (int off = 1; off < 64; off <<= 1) {
        s += __shfl_xor(s, off);
        ss += __shfl_xor(ss, off);
    }
    __shared__ float sh[4];
    const int wv = t >> 6;
    if ((t & 63) == 0) { sh[wv] = s; sh[2 + wv] = ss; }
    __syncthreads();
    s = sh[0] + sh[1];
    ss = sh[2] + sh[3];
    const float mu = s * (1.0f / CDIM);
    const float var = ss * (1.0f / CDIM) - mu * mu;
    const float rs = rsqrtf(var + 1e-6f);
    short* yr = y + (size_t)row * CDIM;
    yr[t]       = f2bf((v0 - mu) * rs * g[t]       + bta[t]);
    yr[t + 128] = f2bf((v1 - mu) * rs * g[t + 128] + bta[t + 128]);
    yr[t + 256] = f2bf((v2 - mu) * rs * g[t + 256] + bta[t + 256]);
}

// -------------------- bf16 MFMA GEMM: C = A[M,K] @ WT[N,K]^T + bias ----------------
// BK=64. MT=4: 128x128 (2x2 waves). MT=1: 64x64 (4x1 waves, balanced grids for N=384).
// MODE 0: fp32 out (+optional resid).  MODE 1: gelu -> bf16 out.  MODE 2: qkv scatter.
template <int MODE, int MT>
__global__ __launch_bounds__(256) void mfma_gemm(const short* __restrict__ A,
                                                 const short* __restrict__ WT,
                                                 const float* __restrict__ bias,
                                                 const float* __restrict__ resid,
                                                 float* __restrict__ outF,
                                                 short* __restrict__ outB,
                                                 short* __restrict__ qb,
                                                 short* __restrict__ kb,
                                                 short* __restrict__ vtb,
                                                 int M, int N, int K) {
    constexpr int BN = (MT == 4) ? 128 : 64;
    constexpr int BM = (MT == 1) ? 64 : 128;
    __shared__ __align__(16) short As[BM * 64];
    __shared__ __align__(16) short Bs[BN * 64];

    const int tid  = threadIdx.x;
    const int w    = tid >> 6;
    const int lane = tid & 63;
    const int quad = lane >> 4;
    const int n15  = lane & 15;
    const int wr   = (MT == 4) ? (w >> 1) : w;
    const int wc   = (MT == 4) ? (w & 1) : 0;
    const int m0   = blockIdx.y * BM;
    const int n0   = blockIdx.x * BN;
    const int swz  = n15 & 7;    // fragment-read swizzle (row&7 == n15&7)

    f32x4 acc[MT][4];
#pragma unroll
    for (int i = 0; i < MT; ++i)
#pragma unroll
        for (int j = 0; j < 4; ++j) {
            acc[i][j][0] = 0; acc[i][j][1] = 0; acc[i][j][2] = 0; acc[i][j][3] = 0;
        }

    for (int k0 = 0; k0 < K; k0 += 64) {
        __syncthreads();
        // tiles: rows x 8 chunks (16B); phys chunk p holds logical p^(r&7)
#pragma unroll
        for (int i = 0; i < BM / 32; ++i) {
            const int c = i * 256 + tid;
            const int r = c >> 3, p = c & 7;
            gl_lds16(A + (size_t)(m0 + r) * K + k0 + ((p ^ (r & 7)) * 8),
                     As + (i * 256 + w * 64) * 8);
        }
#pragma unroll
        for (int i = 0; i < BN / 32; ++i) {
            const int c = i * 256 + tid;
            const int r = c >> 3, p = c & 7;
            gl_lds16(WT + (size_t)(n0 + r) * K + k0 + ((p ^ (r & 7)) * 8),
                     Bs + (i * 256 + w * 64) * 8);
        }
        __syncthreads();

#pragma unroll
        for (int kk = 0; kk < 2; ++kk) {
            bf16x8 af[MT], bfr[4];
#pragma unroll
            for (int mt = 0; mt < MT; ++mt)
                af[mt] = *(const bf16x8*)&As[(wr * (MT * 16) + mt * 16 + n15) * 64 +
                                             (((kk * 4 + quad) ^ swz) * 8)];
#pragma unroll
            for (int nt = 0; nt < 4; ++nt)
                bfr[nt] = *(const bf16x8*)&Bs[(wc * 64 + nt * 16 + n15) * 64 +
                                              (((kk * 4 + quad) ^ swz) * 8)];
#pragma unroll
            for (int mt = 0; mt < MT; ++mt)
#pragma unroll
                for (int nt = 0; nt < 4; ++nt)
                    acc[mt][nt] = __builtin_amdgcn_mfma_f32_16x16x32_bf16(af[mt], bfr[nt], acc[mt][nt], 0, 0, 0);
        }
    }

    // epilogue: row = m0 + wr*(MT*16) + mt*16 + quad*4 + rr, col = n0 + wc*64 + nt*16 + n15
#pragma unroll
    for (int nt = 0; nt < 4; ++nt) {
        const int col = n0 + wc * 64 + nt * 16 + n15;
        const float bv = bias[col];
        if constexpr (MODE == 2) {
            const int part = col / CDIM;
            const int rem  = col - part * CDIM;
            const int h    = rem >> 6;
            const int d    = rem & 63;
#pragma unroll
            for (int mt = 0; mt < MT; ++mt) {
                const int r0 = m0 + wr * (MT * 16) + mt * 16 + quad * 4;   // rr=0 row
                const int bi = r0 >> 11;
                const int n  = r0 & 2047;                                   // 4-aligned
                if (part == 2) {
                    short4 pkv;
                    pkv.x = f2bf(acc[mt][nt][0] + bv);
                    pkv.y = f2bf(acc[mt][nt][1] + bv);
                    pkv.z = f2bf(acc[mt][nt][2] + bv);
                    pkv.w = f2bf(acc[mt][nt][3] + bv);
                    *(short4*)&vtb[((size_t)(bi * HEADS + h) * DH + d) * SEQ + n] = pkv;
                } else {
                    short* dst = (part == 0 ? qb : kb) +
                                 ((size_t)(bi * HEADS + h) * SEQ + n) * DH + d;
#pragma unroll
                    for (int rr = 0; rr < 4; ++rr) {
                        float o = acc[mt][nt][rr] + bv;
                        if (part == 0) o *= QSCALE;   // attention scale + log2e folding
                        dst[(size_t)rr * DH] = f2bf(o);
                    }
                }
            }
        } else {
#pragma unroll
            for (int mt = 0; mt < MT; ++mt)
#pragma unroll
                for (int rr = 0; rr < 4; ++rr) {
                    const int r = m0 + wr * (MT * 16) + mt * 16 + quad * 4 + rr;
                    float o = acc[mt][nt][rr] + bv;
                    if constexpr (MODE == 1) {
                        outB[(size_t)r * N + col] = f2bf(gelu_fast(o));
                    } else {
                        if (resid) o += resid[(size_t)r * N + col];
                        outF[(size_t)r * N + col] = o;
                    }
                }
        }
    }
}

// ---------- bf16 MFMA flash attention: split counted-vmcnt pipeline, 32x32 compute ----------
// r4 (58.5us): r0 staging + 32x32 body; vmcnt(0) drain = ~26% of cycles unhidden.
// Now: the drain splits into two counted halves with ZERO extra LDS/VGPR. QK only needs
// the K tile, PV only needs V. Per iter: wait vmcnt(4) [K(t) landed, V(t) in flight] ->
// K frags to regs -> lgkmcnt(0) -> reissue K(t+1) into the SAME buffer (frags are in regs;
// DMA lands >=200cyc later; next read gated by next counted wait) -> QK MFMAs ->
// wait vmcnt(4) [V(t) landed] -> V frags -> reissue V(t+1) -> softmax+PV. Each tile's
// loads get ~a full iteration of compute to cover L2 latency; occupancy unchanged
// (33.8KB LDS, 4 blocks/CU = 16 waves/CU).
// Also: l-sum moves VALU->MFMA via ones-row trick: Lc = mfma(ones, pf, Lc) gives
// D[m][q] = sum_k P^T[k][q] for every m -> lane l31 reads Lc[0] directly (kills the
// 15-add tree AND the shfl fold). 2 extra MFMA on a 17%-busy pipe.
__global__ __launch_bounds__(256, 4) void attn_mfma(const short* __restrict__ qb,
                                                    const short* __restrict__ kb,
                                                    const short* __restrict__ vtb,
                                                    short* __restrict__ outp) {
    // LDS 33792 B: loop:  wave w: K tile 4KB + V tile 4KB at w*8192
    //              merge: 4 x [32][65] fp32 O partials (33280 B) + 4x32 l
    __shared__ __align__(16) char smem[33792];

    // XCD-local decode: 8 slots x 3 heads x 64 q-tiles of 32 rows
    const int bid = blockIdx.x;
    const int x   = bid & 7;
    const int j   = bid >> 3;              // 0..191
    const int bh  = x * 3 + (j >> 6);      // 0..23
    const int qt  = j & 63;                // 32-row tile index
    const int bi  = bh / HEADS;
    const int h   = bh - bi * HEADS;

    const int tid  = threadIdx.x;
    const int w    = tid >> 6;             // 0..3
    const int lane = tid & 63;
    const int l31  = lane & 31;
    const int hi   = lane >> 5;

    short* Kl  = (short*)(smem + w * 8192);
    short* Vtl = (short*)(smem + w * 8192 + 4096);

    const size_t headoff = (size_t)bh * SEQ * DH;

    // Q B-fragments (loop-invariant, one-time read): col n = q = l31, k = kc*16 + hi*8 + j
    bf16x8 qf[4];
    {
        const short* qg = qb + headoff + (size_t)(qt * 32 + l31) * DH + hi * 8;
#pragma unroll
        for (int kc = 0; kc < 4; ++kc)
            qf[kc] = *(const bf16x8*)(qg + kc * 16);
    }
    // drain Q loads so in-loop vmcnt counting is exact
    asm volatile("s_waitcnt vmcnt(0)" ::: "memory");

    // staging bases (pre-swizzled sources):
    // K tile: 32 ktok x 64 shorts, phys chunk p holds logical p^(row&7) -> 4 gl_lds16
    // V tile: 64 d x 32 shorts,    phys chunk p holds logical p^(row&3) -> 4 gl_lds16
    const int l3 = lane >> 3, l7 = lane & 7;
    const int l2 = lane >> 2, p4 = lane & 3;
    const short* kg = kb + headoff + (size_t)(w * 32 + l3) * DH + ((l7 ^ l3) * 8);
    const short* vg = vtb + (size_t)bh * DH * SEQ + (size_t)l2 * SEQ +
                      ((p4 ^ (l2 & 3)) * 8) + w * 32;

    // fragment-read lane constants
    const int swk = l31 & 7;               // K-tile row swizzle
    const int swv = l31 & 3;               // V-tile row swizzle
    const int krd = l31 * 64;
    const int vrd = l31 * 32;

    f32x16 O0 = {}, O1 = {}, Lc = {};
    const f32x16 Zc = {};

    bf16x8 ones;
    {
        const short one = 0x3F80;          // bf16 1.0
#pragma unroll
        for (int i = 0; i < 8; ++i) ones[i] = one;
    }

#define STAGE_K(tt) { const short* kgt = kg + (size_t)(tt) * 128 * DH;             \
        _Pragma("unroll") for (int i = 0; i < 4; ++i)                              \
            gl_lds16(kgt + i * 512, Kl + i * 512); }
#define STAGE_V(tt) { const short* vgt = vg + (tt) * 128;                          \
        _Pragma("unroll") for (int i = 0; i < 4; ++i)                              \
            gl_lds16(vgt + (size_t)i * 16 * SEQ, Vtl + i * 512); }

    STAGE_K(0);
    STAGE_V(0);

    for (int t = 0; t < SEQ / 128; ++t) {       // 16 iters; wave-private 32-ktok window
        // K(t) landed: oldest 4 of 8 outstanding (V(t) stays in flight)
        asm volatile("s_waitcnt vmcnt(4)" ::: "memory");
        __builtin_amdgcn_sched_barrier(0);

        // K A-frags: m=ktok=l31, k=d=kc*16+hi*8+j -> logical chunk kc*2+hi
        bf16x8 kf0 = *(const bf16x8*)&Kl[krd + (((0 + hi) ^ swk) * 8)];
        bf16x8 kf1 = *(const bf16x8*)&Kl[krd + (((2 + hi) ^ swk) * 8)];
        bf16x8 kf2 = *(const bf16x8*)&Kl[krd + (((4 + hi) ^ swk) * 8)];
        bf16x8 kf3 = *(const bf16x8*)&Kl[krd + (((6 + hi) ^ swk) * 8)];
        asm volatile("s_waitcnt lgkmcnt(0)" ::: "memory");   // frags in regs
        __builtin_amdgcn_sched_barrier(0);                   // pin: reads above, stage below
        if (t < SEQ / 128 - 1) STAGE_K(t + 1);               // refill same buffer

        // S^T[ktok][q] = K * Q^T over d=64: reg r -> ktok (r&3)+8*(r>>2)+4*hi, col q=l31
        f32x16 S = __builtin_amdgcn_mfma_f32_32x32x16_bf16(kf0, qf[0], Zc, 0, 0, 0);
        S = __builtin_amdgcn_mfma_f32_32x32x16_bf16(kf1, qf[1], S, 0, 0, 0);
        S = __builtin_amdgcn_mfma_f32_32x32x16_bf16(kf2, qf[2], S, 0, 0, 0);
        S = __builtin_amdgcn_mfma_f32_32x32x16_bf16(kf3, qf[3], S, 0, 0, 0);

        // V(t) landed (it precedes K(t+1) in the vm queue)
        if (t < SEQ / 128 - 1) {
            asm volatile("s_waitcnt vmcnt(4)" ::: "memory");
        } else {
            asm volatile("s_waitcnt vmcnt(0)" ::: "memory");
        }
        __builtin_amdgcn_sched_barrier(0);

        // V^T A-frags: m=d=l31(+32), k=ktok chunk (v00/v10: hi, v01/v11: 2+hi)
        bf16x8 v00 = *(const bf16x8*)&Vtl[vrd + ((hi ^ swv) * 8)];
        bf16x8 v01 = *(const bf16x8*)&Vtl[vrd + (((2 + hi) ^ swv) * 8)];
        bf16x8 v10 = *(const bf16x8*)&Vtl[1024 + vrd + ((hi ^ swv) * 8)];
        bf16x8 v11 = *(const bf16x8*)&Vtl[1024 + vrd + (((2 + hi) ^ swv) * 8)];
        asm volatile("s_waitcnt lgkmcnt(0)" ::: "memory");
        __builtin_amdgcn_sched_barrier(0);
        if (t < SEQ / 128 - 1) STAGE_V(t + 1);

        // no-max exp2 softmax (scores pre-scaled by 0.125*log2e at qkv epilogue)
        float e[16];
#pragma unroll
        for (int r = 0; r < 16; ++r) e[r] = exp2f(S[r]);

        // P^T B-frags: need k = hi*8+j per 16-ktok chunk; swap(w0,w2) -> frag words 0,2
        int p0 = pack_bf2(e[0], e[1]),  p1 = pack_bf2(e[2], e[3]);
        int p2 = pack_bf2(e[4], e[5]),  p3 = pack_bf2(e[6], e[7]);
        asm("v_permlane32_swap_b32 %0, %1" : "+v"(p0), "+v"(p2));
        asm("v_permlane32_swap_b32 %0, %1" : "+v"(p1), "+v"(p3));
        int p4w = pack_bf2(e[8], e[9]),  p5 = pack_bf2(e[10], e[11]);
        int p6 = pack_bf2(e[12], e[13]), p7 = pack_bf2(e[14], e[15]);
        asm("v_permlane32_swap_b32 %0, %1" : "+v"(p4w), "+v"(p6));
        asm("v_permlane32_swap_b32 %0, %1" : "+v"(p5), "+v"(p7));
        bf16x8 pf0, pf1;
        { int pw[4] = {p0, p1, p2, p3};   __builtin_memcpy(&pf0, pw, 16); }
        { int pw[4] = {p4w, p5, p6, p7};  __builtin_memcpy(&pf1, pw, 16); }

        // O^T[d][q] += V^T * P^T;  Lc[m][q] += sum_k P^T[k][q] (ones-row trick)
        O0 = __builtin_amdgcn_mfma_f32_32x32x16_bf16(v00, pf0, O0, 0, 0, 0);
        O0 = __builtin_amdgcn_mfma_f32_32x32x16_bf16(v01, pf1, O0, 0, 0, 0);
        O1 = __builtin_amdgcn_mfma_f32_32x32x16_bf16(v10, pf0, O1, 0, 0, 0);
        O1 = __builtin_amdgcn_mfma_f32_32x32x16_bf16(v11, pf1, O1, 0, 0, 0);
        Lc = __builtin_amdgcn_mfma_f32_32x32x16_bf16(ones, pf0, Lc, 0, 0, 0);
        Lc = __builtin_amdgcn_mfma_f32_32x32x16_bf16(ones, pf1, Lc, 0, 0, 0);
    }
#undef STAGE_K
#undef STAGE_V

    // ---- merge: cross-wave sum of O^T and l via LDS (one-time) ----
    __syncthreads();                       // all waves done with their K/V tiles
    float* Obuf = (float*)smem;            // wave p partial at p*2080 floats, [32][65]
    float* lbuf = (float*)(smem + 33280);  // [p][32]
    float* myO  = Obuf + w * 2080;
#pragma unroll
    for (int r = 0; r < 16; ++r) {
        const int d0 = (r & 3) + 8 * (r >> 2) + 4 * hi;
        myO[l31 * 65 + d0]      = O0[r];
        myO[l31 * 65 + 32 + d0] = O1[r];
    }
    if (hi == 0) lbuf[w * 32 + l31] = Lc[0];   // every row of Lc holds l[q=l31]
    __syncthreads();

    // wave w sums d-slice [w*16, w*16+16): lane (quad,n15) -> d = w*16+n15, q = quad*8+i
    const int quad = lane >> 4;
    const int n15  = lane & 15;
    const int d = w * 16 + n15;
#pragma unroll
    for (int i = 0; i < 8; ++i) {
        const int q = quad * 8 + i;
        const float l = lbuf[q] + lbuf[32 + q] + lbuf[64 + q] + lbuf[96 + q];
        const float s = Obuf[q * 65 + d] + Obuf[2080 + q * 65 + d] +
                        Obuf[4160 + q * 65 + d] + Obuf[6240 + q * 65 + d];
        outp[(size_t)(bi * SEQ + qt * 32 + q) * CDIM + h * DH + d] = f2bf(s / l);
    }
}

extern "C" void kernel_launch(void* const* d_in, const int* in_sizes, int n_in,
                              void* d_out, int out_size, void* d_ws, size_t ws_size,
                              hipStream_t stream) {
    const float* x      = (const float*)d_in[0];
    const float* w_qkv  = (const float*)d_in[1];
    const float* b_qkv  = (const float*)d_in[2];
    const float* w_proj = (const float*)d_in[3];
    const float* b_proj = (const float*)d_in[4];
    const float* w_fc1  = (const float*)d_in[5];
    const float* b_fc1  = (const float*)d_in[6];
    const float* w_fc2  = (const float*)d_in[7];
    const float* b_fc2  = (const float*)d_in[8];
    const float* g1     = (const float*)d_in[9];
    const float* beta1  = (const float*)d_in[10];
    const float* g2     = (const float*)d_in[11];
    const float* beta2  = (const float*)d_in[12];
    float* out = (float*)d_out;

    short* qkvT = (short*)d_ws;                         // [1152][384]
    short* projT = qkvT + 1152 * 384;                   // [384][384]
    short* fc1T  = projT + 384 * 384;                   // [1536][384]
    short* fc2T  = fc1T + 1536 * 384;                   // [384][1536]
    short* y     = fc2T + 384 * 1536;                   // [TOK][384]
    short* qb    = y + (size_t)TOK * 384;
    short* kb    = qb + (size_t)TOK * 384;
    short* vtb   = kb + (size_t)TOK * 384;
    short* attn  = vtb + (size_t)TOK * 384;             // [TOK][384]
    short* hbuf  = attn + (size_t)TOK * 384;            // [TOK][1536]

    // 1) LN1 + all weight transposes, one launch
    ln_trans<<<TOK + 1728, 128, 0, stream>>>(x, g1, beta1, y,
                                             w_qkv, w_proj, w_fc1, w_fc2,
                                             qkvT, projT, fc1T, fc2T);
    // 2) q/k/vt = y @ w_qkv + b_qkv   (MFMA, scatter epilogue)
    mfma_gemm<2, 4><<<dim3(1152 / 128, TOK / 128), 256, 0, stream>>>(
        y, qkvT, b_qkv, nullptr, nullptr, nullptr, qb, kb, vtb, TOK, 3 * CDIM, CDIM);
    // 3) attn = flash_attention(q, k, vt) -> bf16  (split counted-vmcnt pipeline)
    attn_mfma<<<1536, 256, 0, stream>>>(qb, kb, vtb, attn);
    // 4) out(x1) = x + attn @ w_proj + b_proj
    mfma_gemm<0, 1><<<dim3(CDIM / 64, TOK / 64), 256, 0, stream>>>(
        attn, projT, b_proj, x, out, nullptr, nullptr, nullptr, nullptr, TOK, CDIM, CDIM);
    // 5) y = bf16(LN(out, g2, beta2))
    ln_kernel<<<TOK, 128, 0, stream>>>(out, g2, beta2, y);
    // 6) h = bf16(gelu(y @ w_fc1 + b_fc1))
    mfma_gemm<1, 4><<<dim3(HID / 128, TOK / 128), 256, 0, stream>>>(
        y, fc1T, b_fc1, nullptr, nullptr, hbuf, nullptr, nullptr, nullptr, TOK, HID, CDIM);
    // 7) out = x1 + h @ w_fc2 + b_fc2  (in-place residual)
    mfma_gemm<0, 1><<<dim3(CDIM / 64, TOK / 64), 256, 0, stream>>>(
        hbuf, fc2T, b_fc2, out, out, nullptr, nullptr, nullptr, nullptr, TOK, CDIM, HID);
}

// Round 6
// 227.193 us; speedup vs baseline: 1.1556x; 1.0346x over previous
//
#include <hip/hip_runtime.h>
#include <hip/hip_bf16.h>

#define TOK 8192      // B*N
#define CDIM 384
#define HEADS 6
#define DH 64
#define HID 1536
#define SEQ 2048

// attention scale folded with log2(e): softmax computed in exp2 domain
#define QSCALE 0.18033688011112042f   // 0.125 * log2(e)

typedef short bf16x8 __attribute__((ext_vector_type(8)));
typedef short bf16x4 __attribute__((ext_vector_type(4)));
typedef float f32x4 __attribute__((ext_vector_type(4)));
typedef float f32x16 __attribute__((ext_vector_type(16)));
typedef void __attribute__((address_space(1))) GV;
typedef void __attribute__((address_space(3))) SV;

#if __has_builtin(__builtin_amdgcn_exp2f)
#define EXP2(x) __builtin_amdgcn_exp2f(x)
#else
#define EXP2(x) exp2f(x)
#endif

__device__ __forceinline__ short f2bf(float f) {
    __hip_bfloat16 h = __float2bfloat16(f);
    return *reinterpret_cast<short*>(&h);
}

// hardware packed f32x2 -> bf16x2 (RNE); no builtin on gfx950 -> inline asm (T12 recipe)
__device__ __forceinline__ int cvt_pk_bf16(float lo, float hi) {
    int r;
    asm("v_cvt_pk_bf16_f32 %0, %1, %2" : "=v"(r) : "v"(lo), "v"(hi));
    return r;
}

__device__ __forceinline__ void gl_lds16(const short* g, short* lds) {
    // wave-collective: lane i's 16B -> lds_base + i*16 (lds must be wave-uniform)
    __builtin_amdgcn_global_load_lds((GV*)g, (SV*)lds, 16, 0, 0);
}

// tanh-approx gelu in exp2 domain: gelu(v) = v - v/(1 + exp2(A*v + B*v^3))
__device__ __forceinline__ float gelu_fast(float v) {
    const float A = 2.3022067f;       // 2*log2(e)*0.7978845608
    const float B = 0.1029442f;       // A*0.044715
    const float u = v * (A + B * v * v);
    return v - v / (1.0f + EXP2(u));
}

// ---------- fused LN(x)->bf16 + weight transpose/convert, one launch ----------
__global__ __launch_bounds__(128) void ln_trans(const float* __restrict__ x,
                                                const float* __restrict__ g,
                                                const float* __restrict__ bta,
                                                short* __restrict__ y,
                                                const float* __restrict__ w_qkv,
                                                const float* __restrict__ w_proj,
                                                const float* __restrict__ w_fc1,
                                                const float* __restrict__ w_fc2,
                                                short* __restrict__ qkvT,
                                                short* __restrict__ projT,
                                                short* __restrict__ fc1T,
                                                short* __restrict__ fc2T) {
    if (blockIdx.x < TOK) {
        const int row = blockIdx.x;
        const float* xr = x + (size_t)row * CDIM;
        const int t = threadIdx.x;
        float v0 = xr[t], v1 = xr[t + 128], v2 = xr[t + 256];
        float s = v0 + v1 + v2;
        float ss = v0 * v0 + v1 * v1 + v2 * v2;
#pragma unroll
        for (int off = 1; off < 64; off <<= 1) {
            s += __shfl_xor(s, off);
            ss += __shfl_xor(ss, off);
        }
        __shared__ float sh[4];
        const int wv = t >> 6;
        if ((t & 63) == 0) { sh[wv] = s; sh[2 + wv] = ss; }
        __syncthreads();
        s = sh[0] + sh[1];
        ss = sh[2] + sh[3];
        const float mu = s * (1.0f / CDIM);
        const float var = ss * (1.0f / CDIM) - mu * mu;
        const float rs = rsqrtf(var + 1e-6f);
        short* yr = y + (size_t)row * CDIM;
        yr[t]       = f2bf((v0 - mu) * rs * g[t]       + bta[t]);
        yr[t + 128] = f2bf((v1 - mu) * rs * g[t + 128] + bta[t + 128]);
        yr[t + 256] = f2bf((v2 - mu) * rs * g[t + 256] + bta[t + 256]);
        return;
    }
    int b = blockIdx.x - TOK;
    const float* w; short* o; int K, N, nb;
    if (b < 432)       { w = w_qkv;  o = qkvT;  K = 384;  N = 1152; nb = 36; }
    else if (b < 576)  { b -= 432;  w = w_proj; o = projT; K = 384;  N = 384;  nb = 12; }
    else if (b < 1152) { b -= 576;  w = w_fc1;  o = fc1T;  K = 384;  N = 1536; nb = 48; }
    else               { b -= 1152; w = w_fc2;  o = fc2T;  K = 1536; N = 384;  nb = 12; }
    const int bx = (b % nb) * 32, by = (b / nb) * 32;
    __shared__ float t[32][33];
    const int tx = threadIdx.x & 31, ty = threadIdx.x >> 5;
#pragma unroll
    for (int i = 0; i < 8; ++i)
        t[ty + i * 4][tx] = w[(size_t)(by + ty + i * 4) * N + bx + tx];
    __syncthreads();
#pragma unroll
    for (int i = 0; i < 8; ++i)
        o[(size_t)(bx + ty + i * 4) * K + by + tx] = f2bf(t[tx][ty + i * 4]);
}

// -------------------- LayerNorm (standalone, for LN2) --------------------
__global__ __launch_bounds__(128) void ln_kernel(const float* __restrict__ x,
                                                 const float* __restrict__ g,
                                                 const float* __restrict__ bta,
                                                 short* __restrict__ y) {
    const int row = blockIdx.x;
    const float* xr = x + (size_t)row * CDIM;
    const int t = threadIdx.x;
    float v0 = xr[t], v1 = xr[t + 128], v2 = xr[t + 256];
    float s = v0 + v1 + v2;
    float ss = v0 * v0 + v1 * v1 + v2 * v2;
#pragma unroll
    for (int off = 1; off < 64; off <<= 1) {
        s += __shfl_xor(s, off);
        ss += __shfl_xor(ss, off);
    }
    __shared__ float sh[4];
    const int wv = t >> 6;
    if ((t & 63) == 0) { sh[wv] = s; sh[2 + wv] = ss; }
    __syncthreads();
    s = sh[0] + sh[1];
    ss = sh[2] + sh[3];
    const float mu = s * (1.0f / CDIM);
    const float var = ss * (1.0f / CDIM) - mu * mu;
    const float rs = rsqrtf(var + 1e-6f);
    short* yr = y + (size_t)row * CDIM;
    yr[t]       = f2bf((v0 - mu) * rs * g[t]       + bta[t]);
    yr[t + 128] = f2bf((v1 - mu) * rs * g[t + 128] + bta[t + 128]);
    yr[t + 256] = f2bf((v2 - mu) * rs * g[t + 256] + bta[t + 256]);
}

// -------------------- bf16 MFMA GEMM: C = A[M,K] @ WT[N,K]^T + bias ----------------
// BK=64. MT=4: 128x128 (2x2 waves), original 2-barrier loop (dbuf would need 64KB ->
// occupancy cliff, m132). MT=1: 64x64 (4x1 waves) now DOUBLE-BUFFERED with the T3
// minimum 2-phase recipe: stage(next) -> compute(cur) -> vmcnt(0) + raw s_barrier
// (one barrier/iter; loads get a full compute phase in flight). LDS 32KB -> 5 blocks/CU.
// MODE 0: fp32 out (+optional resid).  MODE 1: gelu -> bf16 out.  MODE 2: qkv scatter.
template <int MODE, int MT>
__global__ __launch_bounds__(256) void mfma_gemm(const short* __restrict__ A,
                                                 const short* __restrict__ WT,
                                                 const float* __restrict__ bias,
                                                 const float* __restrict__ resid,
                                                 float* __restrict__ outF,
                                                 short* __restrict__ outB,
                                                 short* __restrict__ qb,
                                                 short* __restrict__ kb,
                                                 short* __restrict__ vtb,
                                                 int M, int N, int K) {
    constexpr int BN = (MT == 4) ? 128 : 64;
    constexpr int BM = (MT == 1) ? 64 : 128;
    constexpr int BUFS = (MT == 1) ? 2 : 1;
    __shared__ __align__(16) short As[BUFS * BM * 64];
    __shared__ __align__(16) short Bs[BUFS * BN * 64];

    const int tid  = threadIdx.x;
    const int w    = tid >> 6;
    const int lane = tid & 63;
    const int quad = lane >> 4;
    const int n15  = lane & 15;
    const int wr   = (MT == 4) ? (w >> 1) : w;
    const int wc   = (MT == 4) ? (w & 1) : 0;
    const int m0   = blockIdx.y * BM;
    const int n0   = blockIdx.x * BN;
    const int swz  = n15 & 7;    // fragment-read swizzle (row&7 == n15&7)

    f32x4 acc[MT][4];
#pragma unroll
    for (int i = 0; i < MT; ++i)
#pragma unroll
        for (int j = 0; j < 4; ++j) {
            acc[i][j][0] = 0; acc[i][j][1] = 0; acc[i][j][2] = 0; acc[i][j][3] = 0;
        }

    if constexpr (MT == 1) {
        const int nk = K >> 6;
#define STAGE1(buf, k0)                                                        \
    {                                                                          \
        short* Ad = As + (buf) * 4096;                                         \
        short* Bd = Bs + (buf) * 4096;                                         \
        _Pragma("unroll")                                                      \
        for (int i = 0; i < 2; ++i) {                                          \
            const int c = i * 256 + tid;                                       \
            const int r = c >> 3, p = c & 7;                                   \
            gl_lds16(A + (size_t)(m0 + r) * K + (k0) + ((p ^ (r & 7)) * 8),    \
                     Ad + (i * 256 + w * 64) * 8);                             \
        }                                                                      \
        _Pragma("unroll")                                                      \
        for (int i = 0; i < 2; ++i) {                                          \
            const int c = i * 256 + tid;                                       \
            const int r = c >> 3, p = c & 7;                                   \
            gl_lds16(WT + (size_t)(n0 + r) * K + (k0) + ((p ^ (r & 7)) * 8),   \
                     Bd + (i * 256 + w * 64) * 8);                             \
        }                                                                      \
    }
#define COMPUTE1(buf)                                                          \
    {                                                                          \
        const short* Ab = As + (buf) * 4096;                                   \
        const short* Bb = Bs + (buf) * 4096;                                   \
        _Pragma("unroll")                                                      \
        for (int kk = 0; kk < 2; ++kk) {                                       \
            bf16x8 af = *(const bf16x8*)&Ab[(w * 16 + n15) * 64 +              \
                                            (((kk * 4 + quad) ^ swz) * 8)];    \
            bf16x8 bfr[4];                                                     \
            _Pragma("unroll")                                                  \
            for (int nt = 0; nt < 4; ++nt)                                     \
                bfr[nt] = *(const bf16x8*)&Bb[(nt * 16 + n15) * 64 +           \
                                              (((kk * 4 + quad) ^ swz) * 8)];  \
            _Pragma("unroll")                                                  \
            for (int nt = 0; nt < 4; ++nt)                                     \
                acc[0][nt] = __builtin_amdgcn_mfma_f32_16x16x32_bf16(          \
                    af, bfr[nt], acc[0][nt], 0, 0, 0);                         \
        }                                                                      \
    }
        STAGE1(0, 0);
        asm volatile("s_waitcnt vmcnt(0)" ::: "memory");
        __builtin_amdgcn_s_barrier();
        int cur = 0;
        for (int ks = 0; ks < nk - 1; ++ks) {
            STAGE1(cur ^ 1, (ks + 1) << 6);   // next tile's loads in flight under compute
            COMPUTE1(cur);
            asm volatile("s_waitcnt vmcnt(0)" ::: "memory");
            __builtin_amdgcn_s_barrier();
            cur ^= 1;
        }
        COMPUTE1(cur);
#undef STAGE1
#undef COMPUTE1
    } else {
        for (int k0 = 0; k0 < K; k0 += 64) {
            __syncthreads();
            // tiles: rows x 8 chunks (16B); phys chunk p holds logical p^(r&7)
#pragma unroll
            for (int i = 0; i < BM / 32; ++i) {
                const int c = i * 256 + tid;
                const int r = c >> 3, p = c & 7;
                gl_lds16(A + (size_t)(m0 + r) * K + k0 + ((p ^ (r & 7)) * 8),
                         As + (i * 256 + w * 64) * 8);
            }
#pragma unroll
            for (int i = 0; i < BN / 32; ++i) {
                const int c = i * 256 + tid;
                const int r = c >> 3, p = c & 7;
                gl_lds16(WT + (size_t)(n0 + r) * K + k0 + ((p ^ (r & 7)) * 8),
                         Bs + (i * 256 + w * 64) * 8);
            }
            __syncthreads();

#pragma unroll
            for (int kk = 0; kk < 2; ++kk) {
                bf16x8 af[MT], bfr[4];
#pragma unroll
                for (int mt = 0; mt < MT; ++mt)
                    af[mt] = *(const bf16x8*)&As[(wr * (MT * 16) + mt * 16 + n15) * 64 +
                                                 (((kk * 4 + quad) ^ swz) * 8)];
#pragma unroll
                for (int nt = 0; nt < 4; ++nt)
                    bfr[nt] = *(const bf16x8*)&Bs[(wc * 64 + nt * 16 + n15) * 64 +
                                                  (((kk * 4 + quad) ^ swz) * 8)];
#pragma unroll
                for (int mt = 0; mt < MT; ++mt)
#pragma unroll
                    for (int nt = 0; nt < 4; ++nt)
                        acc[mt][nt] = __builtin_amdgcn_mfma_f32_16x16x32_bf16(af[mt], bfr[nt], acc[mt][nt], 0, 0, 0);
            }
        }
    }

    // epilogue: row = m0 + wr*(MT*16) + mt*16 + quad*4 + rr, col = n0 + wc*64 + nt*16 + n15
#pragma unroll
    for (int nt = 0; nt < 4; ++nt) {
        const int col = n0 + wc * 64 + nt * 16 + n15;
        const float bv = bias[col];
        if constexpr (MODE == 2) {
            const int part = col / CDIM;
            const int rem  = col - part * CDIM;
            const int h    = rem >> 6;
            const int d    = rem & 63;
#pragma unroll
            for (int mt = 0; mt < MT; ++mt) {
                const int r0 = m0 + wr * (MT * 16) + mt * 16 + quad * 4;   // rr=0 row
                const int bi = r0 >> 11;
                const int n  = r0 & 2047;                                   // 4-aligned
                if (part == 2) {
                    short4 pkv;
                    pkv.x = f2bf(acc[mt][nt][0] + bv);
                    pkv.y = f2bf(acc[mt][nt][1] + bv);
                    pkv.z = f2bf(acc[mt][nt][2] + bv);
                    pkv.w = f2bf(acc[mt][nt][3] + bv);
                    *(short4*)&vtb[((size_t)(bi * HEADS + h) * DH + d) * SEQ + n] = pkv;
                } else {
                    short* dst = (part == 0 ? qb : kb) +
                                 ((size_t)(bi * HEADS + h) * SEQ + n) * DH + d;
#pragma unroll
                    for (int rr = 0; rr < 4; ++rr) {
                        float o = acc[mt][nt][rr] + bv;
                        if (part == 0) o *= QSCALE;   // attention scale + log2e folding
                        dst[(size_t)rr * DH] = f2bf(o);
                    }
                }
            }
        } else {
#pragma unroll
            for (int mt = 0; mt < MT; ++mt)
#pragma unroll
                for (int rr = 0; rr < 4; ++rr) {
                    const int r = m0 + wr * (MT * 16) + mt * 16 + quad * 4 + rr;
                    float o = acc[mt][nt][rr] + bv;
                    if constexpr (MODE == 1) {
                        outB[(size_t)r * N + col] = f2bf(gelu_fast(o));
                    } else {
                        if (resid) o += resid[(size_t)r * N + col];
                        outF[(size_t)r * N + col] = o;
                    }
                }
        }
    }
}

// ---------- bf16 MFMA flash attention: split counted-vmcnt pipeline, 32x32 compute ----------
// r4/r5 (58.5us): VALU-issue-bound (VALUBusy 56%, MfmaUtil 22%). r5's counted-vmcnt split
// was neutral -> drain wasn't binding; VALU is. This round cuts VALU: the software
// __float22bfloat162_rn pack (~10 ops/pair) -> hardware v_cvt_pk_bf16_f32 (1 op/pair),
// and exp2f -> native v_exp_f32 via builtin. Structure unchanged from r5.
__global__ __launch_bounds__(256, 4) void attn_mfma(const short* __restrict__ qb,
                                                    const short* __restrict__ kb,
                                                    const short* __restrict__ vtb,
                                                    short* __restrict__ outp) {
    // LDS 33792 B: loop:  wave w: K tile 4KB + V tile 4KB at w*8192
    //              merge: 4 x [32][65] fp32 O partials (33280 B) + 4x32 l
    __shared__ __align__(16) char smem[33792];

    // XCD-local decode: 8 slots x 3 heads x 64 q-tiles of 32 rows
    const int bid = blockIdx.x;
    const int x   = bid & 7;
    const int j   = bid >> 3;              // 0..191
    const int bh  = x * 3 + (j >> 6);      // 0..23
    const int qt  = j & 63;                // 32-row tile index
    const int bi  = bh / HEADS;
    const int h   = bh - bi * HEADS;

    const int tid  = threadIdx.x;
    const int w    = tid >> 6;             // 0..3
    const int lane = tid & 63;
    const int l31  = lane & 31;
    const int hi   = lane >> 5;

    short* Kl  = (short*)(smem + w * 8192);
    short* Vtl = (short*)(smem + w * 8192 + 4096);

    const size_t headoff = (size_t)bh * SEQ * DH;

    // Q B-fragments (loop-invariant, one-time read): col n = q = l31, k = kc*16 + hi*8 + j
    bf16x8 qf[4];
    {
        const short* qg = qb + headoff + (size_t)(qt * 32 + l31) * DH + hi * 8;
#pragma unroll
        for (int kc = 0; kc < 4; ++kc)
            qf[kc] = *(const bf16x8*)(qg + kc * 16);
    }
    // drain Q loads so in-loop vmcnt counting is exact
    asm volatile("s_waitcnt vmcnt(0)" ::: "memory");

    // staging bases (pre-swizzled sources):
    // K tile: 32 ktok x 64 shorts, phys chunk p holds logical p^(row&7) -> 4 gl_lds16
    // V tile: 64 d x 32 shorts,    phys chunk p holds logical p^(row&3) -> 4 gl_lds16
    const int l3 = lane >> 3, l7 = lane & 7;
    const int l2 = lane >> 2, p4 = lane & 3;
    const short* kg = kb + headoff + (size_t)(w * 32 + l3) * DH + ((l7 ^ l3) * 8);
    const short* vg = vtb + (size_t)bh * DH * SEQ + (size_t)l2 * SEQ +
                      ((p4 ^ (l2 & 3)) * 8) + w * 32;

    // fragment-read lane constants
    const int swk = l31 & 7;               // K-tile row swizzle
    const int swv = l31 & 3;               // V-tile row swizzle
    const int krd = l31 * 64;
    const int vrd = l31 * 32;

    f32x16 O0 = {}, O1 = {}, Lc = {};
    const f32x16 Zc = {};

    bf16x8 ones;
    {
        const short one = 0x3F80;          // bf16 1.0
#pragma unroll
        for (int i = 0; i < 8; ++i) ones[i] = one;
    }

#define STAGE_K(tt) { const short* kgt = kg + (size_t)(tt) * 128 * DH;             \
        _Pragma("unroll") for (int i = 0; i < 4; ++i)                              \
            gl_lds16(kgt + i * 512, Kl + i * 512); }
#define STAGE_V(tt) { const short* vgt = vg + (tt) * 128;                          \
        _Pragma("unroll") for (int i = 0; i < 4; ++i)                              \
            gl_lds16(vgt + (size_t)i * 16 * SEQ, Vtl + i * 512); }

    STAGE_K(0);
    STAGE_V(0);

    for (int t = 0; t < SEQ / 128; ++t) {       // 16 iters; wave-private 32-ktok window
        // K(t) landed: oldest 4 of 8 outstanding (V(t) stays in flight)
        asm volatile("s_waitcnt vmcnt(4)" ::: "memory");
        __builtin_amdgcn_sched_barrier(0);

        // K A-frags: m=ktok=l31, k=d=kc*16+hi*8+j -> logical chunk kc*2+hi
        bf16x8 kf0 = *(const bf16x8*)&Kl[krd + (((0 + hi) ^ swk) * 8)];
        bf16x8 kf1 = *(const bf16x8*)&Kl[krd + (((2 + hi) ^ swk) * 8)];
        bf16x8 kf2 = *(const bf16x8*)&Kl[krd + (((4 + hi) ^ swk) * 8)];
        bf16x8 kf3 = *(const bf16x8*)&Kl[krd + (((6 + hi) ^ swk) * 8)];
        asm volatile("s_waitcnt lgkmcnt(0)" ::: "memory");   // frags in regs
        __builtin_amdgcn_sched_barrier(0);                   // pin: reads above, stage below
        if (t < SEQ / 128 - 1) STAGE_K(t + 1);               // refill same buffer

        // S^T[ktok][q] = K * Q^T over d=64: reg r -> ktok (r&3)+8*(r>>2)+4*hi, col q=l31
        f32x16 S = __builtin_amdgcn_mfma_f32_32x32x16_bf16(kf0, qf[0], Zc, 0, 0, 0);
        S = __builtin_amdgcn_mfma_f32_32x32x16_bf16(kf1, qf[1], S, 0, 0, 0);
        S = __builtin_amdgcn_mfma_f32_32x32x16_bf16(kf2, qf[2], S, 0, 0, 0);
        S = __builtin_amdgcn_mfma_f32_32x32x16_bf16(kf3, qf[3], S, 0, 0, 0);

        // V(t) landed (it precedes K(t+1) in the vm queue)
        if (t < SEQ / 128 - 1) {
            asm volatile("s_waitcnt vmcnt(4)" ::: "memory");
        } else {
            asm volatile("s_waitcnt vmcnt(0)" ::: "memory");
        }
        __builtin_amdgcn_sched_barrier(0);

        // V^T A-frags: m=d=l31(+32), k=ktok chunk (v00/v10: hi, v01/v11: 2+hi)
        bf16x8 v00 = *(const bf16x8*)&Vtl[vrd + ((hi ^ swv) * 8)];
        bf16x8 v01 = *(const bf16x8*)&Vtl[vrd + (((2 + hi) ^ swv) * 8)];
        bf16x8 v10 = *(const bf16x8*)&Vtl[1024 + vrd + ((hi ^ swv) * 8)];
        bf16x8 v11 = *(const bf16x8*)&Vtl[1024 + vrd + (((2 + hi) ^ swv) * 8)];
        asm volatile("s_waitcnt lgkmcnt(0)" ::: "memory");
        __builtin_amdgcn_sched_barrier(0);
        if (t < SEQ / 128 - 1) STAGE_V(t + 1);

        // no-max exp2 softmax (scores pre-scaled by 0.125*log2e at qkv epilogue)
        float e[16];
#pragma unroll
        for (int r = 0; r < 16; ++r) e[r] = EXP2(S[r]);

        // P^T B-frags via HW cvt_pk (1 instr/pair) + permlane32_swap:
        // need k = hi*8+j per 16-ktok chunk; swap(w0,w2) -> frag words 0,2
        int p0 = cvt_pk_bf16(e[0], e[1]),   p1 = cvt_pk_bf16(e[2], e[3]);
        int p2 = cvt_pk_bf16(e[4], e[5]),   p3 = cvt_pk_bf16(e[6], e[7]);
        asm("v_permlane32_swap_b32 %0, %1" : "+v"(p0), "+v"(p2));
        asm("v_permlane32_swap_b32 %0, %1" : "+v"(p1), "+v"(p3));
        int p4w = cvt_pk_bf16(e[8], e[9]),  p5 = cvt_pk_bf16(e[10], e[11]);
        int p6 = cvt_pk_bf16(e[12], e[13]), p7 = cvt_pk_bf16(e[14], e[15]);
        asm("v_permlane32_swap_b32 %0, %1" : "+v"(p4w), "+v"(p6));
        asm("v_permlane32_swap_b32 %0, %1" : "+v"(p5), "+v"(p7));
        bf16x8 pf0, pf1;
        { int pw[4] = {p0, p1, p2, p3};   __builtin_memcpy(&pf0, pw, 16); }
        { int pw[4] = {p4w, p5, p6, p7};  __builtin_memcpy(&pf1, pw, 16); }

        // O^T[d][q] += V^T * P^T;  Lc[m][q] += sum_k P^T[k][q] (ones-row trick)
        O0 = __builtin_amdgcn_mfma_f32_32x32x16_bf16(v00, pf0, O0, 0, 0, 0);
        O0 = __builtin_amdgcn_mfma_f32_32x32x16_bf16(v01, pf1, O0, 0, 0, 0);
        O1 = __builtin_amdgcn_mfma_f32_32x32x16_bf16(v10, pf0, O1, 0, 0, 0);
        O1 = __builtin_amdgcn_mfma_f32_32x32x16_bf16(v11, pf1, O1, 0, 0, 0);
        Lc = __builtin_amdgcn_mfma_f32_32x32x16_bf16(ones, pf0, Lc, 0, 0, 0);
        Lc = __builtin_amdgcn_mfma_f32_32x32x16_bf16(ones, pf1, Lc, 0, 0, 0);
    }
#undef STAGE_K
#undef STAGE_V

    // ---- merge: cross-wave sum of O^T and l via LDS (one-time) ----
    __syncthreads();                       // all waves done with their K/V tiles
    float* Obuf = (float*)smem;            // wave p partial at p*2080 floats, [32][65]
    float* lbuf = (float*)(smem + 33280);  // [p][32]
    float* myO  = Obuf + w * 2080;
#pragma unroll
    for (int r = 0; r < 16; ++r) {
        const int d0 = (r & 3) + 8 * (r >> 2) + 4 * hi;
        myO[l31 * 65 + d0]      = O0[r];
        myO[l31 * 65 + 32 + d0] = O1[r];
    }
    if (hi == 0) lbuf[w * 32 + l31] = Lc[0];   // every row of Lc holds l[q=l31]
    __syncthreads();

    // wave w sums d-slice [w*16, w*16+16): lane (quad,n15) -> d = w*16+n15, q = quad*8+i
    const int quad = lane >> 4;
    const int n15  = lane & 15;
    const int d = w * 16 + n15;
#pragma unroll
    for (int i = 0; i < 8; ++i) {
        const int q = quad * 8 + i;
        const float l = lbuf[q] + lbuf[32 + q] + lbuf[64 + q] + lbuf[96 + q];
        const float s = Obuf[q * 65 + d] + Obuf[2080 + q * 65 + d] +
                        Obuf[4160 + q * 65 + d] + Obuf[6240 + q * 65 + d];
        outp[(size_t)(bi * SEQ + qt * 32 + q) * CDIM + h * DH + d] = f2bf(s / l);
    }
}

extern "C" void kernel_launch(void* const* d_in, const int* in_sizes, int n_in,
                              void* d_out, int out_size, void* d_ws, size_t ws_size,
                              hipStream_t stream) {
    const float* x      = (const float*)d_in[0];
    const float* w_qkv  = (const float*)d_in[1];
    const float* b_qkv  = (const float*)d_in[2];
    const float* w_proj = (const float*)d_in[3];
    const float* b_proj = (const float*)d_in[4];
    const float* w_fc1  = (const float*)d_in[5];
    const float* b_fc1  = (const float*)d_in[6];
    const float* w_fc2  = (const float*)d_in[7];
    const float* b_fc2  = (const float*)d_in[8];
    const float* g1     = (const float*)d_in[9];
    const float* beta1  = (const float*)d_in[10];
    const float* g2     = (const float*)d_in[11];
    const float* beta2  = (const float*)d_in[12];
    float* out = (float*)d_out;

    short* qkvT = (short*)d_ws;                         // [1152][384]
    short* projT = qkvT + 1152 * 384;                   // [384][384]
    short* fc1T  = projT + 384 * 384;                   // [1536][384]
    short* fc2T  = fc1T + 1536 * 384;                   // [384][1536]
    short* y     = fc2T + 384 * 1536;                   // [TOK][384]
    short* qb    = y + (size_t)TOK * 384;
    short* kb    = qb + (size_t)TOK * 384;
    short* vtb   = kb + (size_t)TOK * 384;
    short* attn  = vtb + (size_t)TOK * 384;             // [TOK][384]
    short* hbuf  = attn + (size_t)TOK * 384;            // [TOK][1536]

    // 1) LN1 + all weight transposes, one launch
    ln_trans<<<TOK + 1728, 128, 0, stream>>>(x, g1, beta1, y,
                                             w_qkv, w_proj, w_fc1, w_fc2,
                                             qkvT, projT, fc1T, fc2T);
    // 2) q/k/vt = y @ w_qkv + b_qkv   (MFMA, scatter epilogue)
    mfma_gemm<2, 4><<<dim3(1152 / 128, TOK / 128), 256, 0, stream>>>(
        y, qkvT, b_qkv, nullptr, nullptr, nullptr, qb, kb, vtb, TOK, 3 * CDIM, CDIM);
    // 3) attn = flash_attention(q, k, vt) -> bf16  (split counted-vmcnt pipeline)
    attn_mfma<<<1536, 256, 0, stream>>>(qb, kb, vtb, attn);
    // 4) out(x1) = x + attn @ w_proj + b_proj   (dbuf 2-phase MT=1)
    mfma_gemm<0, 1><<<dim3(CDIM / 64, TOK / 64), 256, 0, stream>>>(
        attn, projT, b_proj, x, out, nullptr, nullptr, nullptr, nullptr, TOK, CDIM, CDIM);
    // 5) y = bf16(LN(out, g2, beta2))
    ln_kernel<<<TOK, 128, 0, stream>>>(out, g2, beta2, y);
    // 6) h = bf16(gelu(y @ w_fc1 + b_fc1))
    mfma_gemm<1, 4><<<dim3(HID / 128, TOK / 128), 256, 0, stream>>>(
        y, fc1T, b_fc1, nullptr, nullptr, hbuf, nullptr, nullptr, nullptr, TOK, HID, CDIM);
    // 7) out = x1 + h @ w_fc2 + b_fc2  (in-place residual, dbuf 2-phase MT=1)
    mfma_gemm<0, 1><<<dim3(CDIM / 64, TOK / 64), 256, 0, stream>>>(
        hbuf, fc2T, b_fc2, out, out, nullptr, nullptr, nullptr, nullptr, TOK, CDIM, HID);
}